// Round 3
// baseline (389.329 us; speedup 1.0000x reference)
//
#include <hip/hip_runtime.h>

// MultiHeadedAttention: B=4, S=2048, H=16, D_K=64, D_MODEL=1024
// Pipeline: [gemm_qkv] -> [flash attn] -> [gemm_out]
// ws layout (64MB):
//   q_ws [64][2048][64] bf16 @ 0      (16 MB)  (pre-scaled by 0.125*log2e)
//   k_ws [64][2048][64] bf16 @ 16MB   (16 MB)
//   vT   [64][64][2048] bf16 @ 32MB   (16 MB)  (V transposed per head: [bh][d][s])
//   o_ws [4][2048][1024] bf16 @ 48MB  (16 MB)

#define DMODEL 1024
#define SLEN 2048
#define NHEAD 16
#define LOG2E 1.44269504088896340736f

typedef __attribute__((ext_vector_type(4))) float f32x4;
typedef __attribute__((ext_vector_type(8))) short bf16x8;
typedef __attribute__((ext_vector_type(4))) int i32x4;
typedef __attribute__((ext_vector_type(2))) int i32x2;

__device__ __forceinline__ unsigned short f2bf(float f) {
  __bf16 h = (__bf16)f;
  union { __bf16 h; unsigned short u; } cv; cv.h = h; return cv.u;
}
__device__ __forceinline__ unsigned pk(float a, float b) {
  return (unsigned)f2bf(a) | ((unsigned)f2bf(b) << 16);
}
__device__ __forceinline__ float fexp2(float x) {
#if __has_builtin(__builtin_amdgcn_exp2f)
  return __builtin_amdgcn_exp2f(x);
#else
  return exp2f(x);
#endif
}
__device__ __forceinline__ f32x4 zero4() {
  f32x4 z; z[0] = 0.f; z[1] = 0.f; z[2] = 0.f; z[3] = 0.f; return z;
}
// async global->LDS, 16B per lane; lds dest wave-uniform base + lane*16
__device__ __forceinline__ void gload16(const void* g, void* l) {
  __builtin_amdgcn_global_load_lds(
      (const __attribute__((address_space(1))) unsigned int*)(uintptr_t)g,
      (__attribute__((address_space(3))) unsigned int*)(uintptr_t)l, 16, 0, 0);
}

// ---------------------------------------------------------------------------
// QKV projection: Y = X @ W^T + b ; M=8192,N=1024,K=1024 per z; out bf16
// per-head layout. BK=64, XOR-swizzled LDS (T2), XCD-chunked grid (T1),
// register prefetch of next tile. z==2: V^T transpose epilogue.
// ---------------------------------------------------------------------------
__global__ __launch_bounds__(256)
void gemm_qkv(const float* __restrict__ xq, const float* __restrict__ xk,
              const float* __restrict__ xv,
              const float* __restrict__ Wq, const float* __restrict__ bq,
              const float* __restrict__ Wk, const float* __restrict__ bk,
              const float* __restrict__ Wv, const float* __restrict__ bv,
              unsigned short* __restrict__ qw, unsigned short* __restrict__ kw,
              unsigned short* __restrict__ vw)
{
  // T1: XCD-chunked bijective remap (1536 = 8 * 192), n fastest within chunk
  const int bid = blockIdx.x;
  const int wg = (bid & 7) * 192 + (bid >> 3);
  const int z = wg >> 9;
  const int r = wg & 511;
  const int m0 = (r >> 3) * 128;
  const int n0 = (r & 7) * 128;

  const float* __restrict__ X    = (z == 0) ? xq : (z == 1) ? xk : xv;
  const float* __restrict__ W    = (z == 0) ? Wq : (z == 1) ? Wk : Wv;
  const float* __restrict__ bias = (z == 0) ? bq : (z == 1) ? bk : bv;
  const float scale = (z == 0) ? 0.125f * LOG2E : 1.0f;

  const int tid = threadIdx.x;
  const int lane = tid & 63, wid = tid >> 6;
  const int l15 = lane & 15, g = lane >> 4;
  const int wr = wid >> 1, wc = wid & 1;

  __shared__ __align__(16) unsigned short SM[2 * 128 * 64];  // Al | Bl (32 KB)
  char* Al = (char*)SM;
  char* Bl = (char*)(SM + 128 * 64);
  unsigned short* TT = SM;                                   // [64][136] overlay

  const int arow = tid >> 1, ahalf = tid & 1;   // 2 thr/row, 32 floats each
  const float* __restrict__ Ag = X + (size_t)(m0 + arow) * DMODEL + ahalf * 32;
  const float* __restrict__ Bg = W + (size_t)(n0 + arow) * DMODEL + ahalf * 32;
  const unsigned wswz = ((unsigned)(arow & 7)) << 4;
  const unsigned rswz = ((unsigned)(l15 & 7)) << 4;

  f32x4 acc[4][4];
#pragma unroll
  for (int i = 0; i < 4; ++i)
#pragma unroll
    for (int j = 0; j < 4; ++j) acc[i][j] = zero4();

  f32x4 ar8[8], br8[8];
#pragma unroll
  for (int j = 0; j < 8; ++j) {
    ar8[j] = *(const f32x4*)(Ag + j * 4);
    br8[j] = *(const f32x4*)(Bg + j * 4);
  }

  for (int kt = 0; kt < 16; ++kt) {
    __syncthreads();                       // previous compute done
#pragma unroll
    for (int j = 0; j < 4; ++j) {
      i32x4 wa, wb;
      wa[0] = (int)pk(ar8[2*j][0], ar8[2*j][1]);
      wa[1] = (int)pk(ar8[2*j][2], ar8[2*j][3]);
      wa[2] = (int)pk(ar8[2*j+1][0], ar8[2*j+1][1]);
      wa[3] = (int)pk(ar8[2*j+1][2], ar8[2*j+1][3]);
      wb[0] = (int)pk(br8[2*j][0], br8[2*j][1]);
      wb[1] = (int)pk(br8[2*j][2], br8[2*j][3]);
      wb[2] = (int)pk(br8[2*j+1][0], br8[2*j+1][1]);
      wb[3] = (int)pk(br8[2*j+1][2], br8[2*j+1][3]);
      const unsigned off = (unsigned)(arow * 128) + (((unsigned)(ahalf * 64 + j * 16)) ^ wswz);
      *(i32x4*)(Al + off) = wa;
      *(i32x4*)(Bl + off) = wb;
    }
    __syncthreads();                       // tile staged
    if (kt < 15) {                         // prefetch next tile into regs
      const float* Ap = Ag + (kt + 1) * 64;
      const float* Bp = Bg + (kt + 1) * 64;
#pragma unroll
      for (int j = 0; j < 8; ++j) {
        ar8[j] = *(const f32x4*)(Ap + j * 4);
        br8[j] = *(const f32x4*)(Bp + j * 4);
      }
    }
#pragma unroll
    for (int kh = 0; kh < 2; ++kh) {
      bf16x8 afr[4], bfr[4];
      const unsigned cb = ((unsigned)(kh * 64 + g * 16)) ^ rswz;
#pragma unroll
      for (int i = 0; i < 4; ++i) {
        afr[i] = *(const bf16x8*)(Al + (wr * 64 + i * 16 + l15) * 128 + cb);
        bfr[i] = *(const bf16x8*)(Bl + (wc * 64 + i * 16 + l15) * 128 + cb);
      }
#pragma unroll
      for (int mi = 0; mi < 4; ++mi)
#pragma unroll
        for (int ni = 0; ni < 4; ++ni)
          acc[mi][ni] = __builtin_amdgcn_mfma_f32_16x16x32_bf16(
              afr[mi], bfr[ni], acc[mi][ni], 0, 0, 0);
    }
  }

  float bv4[4];
#pragma unroll
  for (int ni = 0; ni < 4; ++ni) bv4[ni] = bias[n0 + wc * 64 + ni * 16 + l15];

  if (z == 2) {
    // ---- transpose epilogue: store V^T [b*1024 + n][s] ----
    const int bb = m0 >> 11, s0 = m0 & 2047;
#pragma unroll
    for (int p = 0; p < 2; ++p) {
      __syncthreads();
      if (wc == p) {
#pragma unroll
        for (int mi = 0; mi < 4; ++mi)
#pragma unroll
          for (int ni = 0; ni < 4; ++ni)
#pragma unroll
            for (int rr2 = 0; rr2 < 4; ++rr2)
              TT[(ni * 16 + l15) * 136 + wr * 64 + mi * 16 + 4 * g + rr2] =
                  f2bf(acc[mi][ni][rr2] + bv4[ni]);
      }
      __syncthreads();
      const int rr = tid >> 2, cc = (tid & 3) * 32;
      unsigned short* dp = vw + ((size_t)(bb * 1024 + n0 + p * 64 + rr)) * 2048 + s0 + cc;
      const unsigned short* sp = &TT[rr * 136 + cc];
#pragma unroll
      for (int j = 0; j < 4; ++j)
        *(i32x4*)(void*)(dp + j * 8) = *(const i32x4*)(const void*)(sp + j * 8);
    }
    return;
  }

  unsigned short* __restrict__ dst = (z == 0) ? qw : kw;
#pragma unroll
  for (int mi = 0; mi < 4; ++mi) {
#pragma unroll
    for (int ni = 0; ni < 4; ++ni) {
      const int n = n0 + wc * 64 + ni * 16 + l15;
      const int h = n >> 6, d = n & 63;
#pragma unroll
      for (int rr2 = 0; rr2 < 4; ++rr2) {
        const int m = m0 + wr * 64 + mi * 16 + 4 * g + rr2;
        const int b = m >> 11, s = m & 2047;
        const float val = (acc[mi][ni][rr2] + bv4[ni]) * scale;
        dst[((size_t)(b * NHEAD + h) * SLEN + s) * 64 + d] = f2bf(val);
      }
    }
  }
}

// ---------------------------------------------------------------------------
// Flash attention. 4 waves x 32 q-rows (QBLK 128). KVBLK 64, double-buffered
// global_load_lds staging with XOR-swizzled source; exp2-domain online softmax
// with defer-max; mask folded into MFMA C-init.  (unchanged from R2)
// ---------------------------------------------------------------------------
__global__ __launch_bounds__(256, 3)
void attn(const unsigned short* __restrict__ q_ws,
          const unsigned short* __restrict__ k_ws,
          const unsigned short* __restrict__ vT,
          const int* __restrict__ mask,
          unsigned short* __restrict__ o_ws)
{
  const int bh = blockIdx.x;            // 0..63
  const int qt = blockIdx.y;            // 0..15
  const int b = bh >> 4, h = bh & 15;
  const int tid = threadIdx.x, w = tid >> 6, lane = tid & 63;
  const int l15 = lane & 15, g = lane >> 4;

  __shared__ __align__(16) unsigned short Kb[2][64 * 64];
  __shared__ __align__(16) unsigned short Vb[2][64 * 64];
  __shared__ __align__(16) unsigned short Pl[4][16 * 64];
  __shared__ __align__(16) float maskf[2048];

  {
    const int4* mp = (const int4*)(mask + b * SLEN);
    const int4 ma = mp[tid * 2], mb = mp[tid * 2 + 1];
    float4 f0, f1;
    f0.x = ma.x ? 0.f : -1e9f; f0.y = ma.y ? 0.f : -1e9f;
    f0.z = ma.z ? 0.f : -1e9f; f0.w = ma.w ? 0.f : -1e9f;
    f1.x = mb.x ? 0.f : -1e9f; f1.y = mb.y ? 0.f : -1e9f;
    f1.z = mb.z ? 0.f : -1e9f; f1.w = mb.w ? 0.f : -1e9f;
    *(float4*)&maskf[tid * 8]     = f0;
    *(float4*)&maskf[tid * 8 + 4] = f1;
  }

  const size_t head = (size_t)bh * SLEN;
  const int r8 = lane >> 3, c8 = lane & 7;
  const int swz = ((c8 ^ r8) * 16);
  const unsigned pswz = (unsigned)((l15 & 7) << 4);

  const int qbase = qt * 128 + w * 32;
  bf16x8 qf[2][2];
  {
    const unsigned short* qp0 = q_ws + (head + qbase + l15) * 64;
    const unsigned short* qp1 = q_ws + (head + qbase + 16 + l15) * 64;
    qf[0][0] = *(const bf16x8*)(qp0 + g * 8);
    qf[0][1] = *(const bf16x8*)(qp0 + 32 + g * 8);
    qf[1][0] = *(const bf16x8*)(qp1 + g * 8);
    qf[1][1] = *(const bf16x8*)(qp1 + 32 + g * 8);
  }

  auto stage = [&](int kt2, int bufi) {
#pragma unroll
    for (int cl = 0; cl < 2; ++cl) {
      const int r = w * 16 + cl * 8 + r8;
      const char* gk = (const char*)(k_ws + (head + kt2 * 64 + r) * 64) + swz;
      gload16(gk, &Kb[bufi][(w * 16 + cl * 8) * 64]);
      const char* gv = (const char*)(vT + ((size_t)(bh * 64 + r)) * SLEN + kt2 * 64) + swz;
      gload16(gv, &Vb[bufi][(w * 16 + cl * 8) * 64]);
    }
  };

  stage(0, 0);
  __syncthreads();

  float m_run[2] = {-1e30f, -1e30f};
  float l_run[2] = {0.f, 0.f};
  f32x4 of[2][4];
#pragma unroll
  for (int qi = 0; qi < 2; ++qi)
#pragma unroll
    for (int n = 0; n < 4; ++n) of[qi][n] = zero4();

  unsigned short* Pw = (unsigned short*)Pl[w];
  int cur = 0;

  for (int kt = 0; kt < 32; ++kt) {
    if (kt + 1 < 32) stage(kt + 1, cur ^ 1);
    const char* Kc = (const char*)Kb[cur];
    const char* Vc = (const char*)Vb[cur];
    const int kv0 = kt * 64;

    f32x4 mv[4];
#pragma unroll
    for (int s = 0; s < 4; ++s) mv[s] = *(const f32x4*)&maskf[kv0 + s * 16 + g * 4];

#pragma unroll
    for (int qi = 0; qi < 2; ++qi) {
      f32x4 sac[4];
#pragma unroll
      for (int s = 0; s < 4; ++s) {
        const char* kr = Kc + (s * 16 + l15) * 128;
        const bf16x8 kf0 = *(const bf16x8*)(kr + ((unsigned)(g * 16) ^ pswz));
        const bf16x8 kf1 = *(const bf16x8*)(kr + ((unsigned)(64 + g * 16) ^ pswz));
        f32x4 zt = mv[s];
        zt = __builtin_amdgcn_mfma_f32_16x16x32_bf16(kf0, qf[qi][0], zt, 0, 0, 0);
        sac[s] = __builtin_amdgcn_mfma_f32_16x16x32_bf16(kf1, qf[qi][1], zt, 0, 0, 0);
      }

      float tmax = -3.0e38f;
#pragma unroll
      for (int s = 0; s < 4; ++s)
#pragma unroll
        for (int rr = 0; rr < 4; ++rr) tmax = fmaxf(tmax, sac[s][rr]);
      tmax = fmaxf(tmax, __shfl_xor(tmax, 16));
      tmax = fmaxf(tmax, __shfl_xor(tmax, 32));
      if (!__all(tmax <= m_run[qi] + 8.f)) {
        const float mnew = fmaxf(m_run[qi], tmax);
        const float alpha = fexp2(m_run[qi] - mnew);
        float af[4];
#pragma unroll
        for (int rr = 0; rr < 4; ++rr) af[rr] = __shfl(alpha, g * 4 + rr);
#pragma unroll
        for (int n = 0; n < 4; ++n)
#pragma unroll
          for (int rr = 0; rr < 4; ++rr) of[qi][n][rr] *= af[rr];
        l_run[qi] *= alpha;
        m_run[qi] = mnew;
      }
      float psum = 0.f;
      unsigned pr[4][2];
#pragma unroll
      for (int s = 0; s < 4; ++s) {
        const float p0 = fexp2(sac[s][0] - m_run[qi]);
        const float p1 = fexp2(sac[s][1] - m_run[qi]);
        const float p2 = fexp2(sac[s][2] - m_run[qi]);
        const float p3 = fexp2(sac[s][3] - m_run[qi]);
        psum += (p0 + p1) + (p2 + p3);
        pr[s][0] = pk(p0, p1); pr[s][1] = pk(p2, p3);
      }
      l_run[qi] += psum;
#pragma unroll
      for (int s = 0; s < 4; ++s) {
        i32x2 wv; wv[0] = (int)pr[s][0]; wv[1] = (int)pr[s][1];
        *(i32x2*)(void*)((char*)Pw + l15 * 128 + ((unsigned)(s * 32 + g * 8) ^ pswz)) = wv;
      }

#pragma unroll
      for (int k2 = 0; k2 < 2; ++k2) {
        const bf16x8 pa = *(const bf16x8*)(const void*)(
            (const char*)Pw + l15 * 128 + ((unsigned)(k2 * 64 + g * 16) ^ pswz));
#pragma unroll
        for (int n = 0; n < 4; ++n) {
          const bf16x8 vf = *(const bf16x8*)(
              Vc + (n * 16 + l15) * 128 + ((unsigned)(k2 * 64 + g * 16) ^ pswz));
          of[qi][n] = __builtin_amdgcn_mfma_f32_16x16x32_bf16(pa, vf, of[qi][n], 0, 0, 0);
        }
      }
    }
    __syncthreads();
    cur ^= 1;
  }

#pragma unroll
  for (int qi = 0; qi < 2; ++qi) {
    float lt = l_run[qi];
    lt += __shfl_xor(lt, 16);
    lt += __shfl_xor(lt, 32);
    float inv[4];
#pragma unroll
    for (int rr = 0; rr < 4; ++rr) inv[rr] = 1.f / __shfl(lt, g * 4 + rr);
    const int qrow0 = qt * 128 + w * 32 + qi * 16;
#pragma unroll
    for (int n = 0; n < 4; ++n) {
      const int d = h * 64 + n * 16 + l15;
#pragma unroll
      for (int rr = 0; rr < 4; ++rr) {
        const int sr = qrow0 + 4 * g + rr;
        o_ws[((size_t)b * SLEN + sr) * DMODEL + d] = f2bf(of[qi][n][rr] * inv[rr]);
      }
    }
  }
}

// ---------------------------------------------------------------------------
// Output projection: out = O @ Wo^T + bo (fp32 out). A already bf16.
// Same BK=64 / T2 / T1 structure as gemm_qkv.
// ---------------------------------------------------------------------------
__global__ __launch_bounds__(256)
void gemm_out(const unsigned short* __restrict__ ow,
              const float* __restrict__ Wo, const float* __restrict__ bo,
              float* __restrict__ out)
{
  const int bid = blockIdx.x;                      // 512 = 8 * 64
  const int wg = (bid & 7) * 64 + (bid >> 3);
  const int m0 = (wg >> 3) * 128;
  const int n0 = (wg & 7) * 128;

  const int tid = threadIdx.x;
  const int lane = tid & 63, wid = tid >> 6;
  const int l15 = lane & 15, g = lane >> 4;
  const int wr = wid >> 1, wc = wid & 1;

  __shared__ __align__(16) unsigned short SM[2 * 128 * 64];
  char* Al = (char*)SM;
  char* Bl = (char*)(SM + 128 * 64);

  const int arow = tid >> 1, ahalf = tid & 1;
  const unsigned short* __restrict__ Ag = ow + (size_t)(m0 + arow) * DMODEL + ahalf * 32;
  const float* __restrict__ Bg = Wo + (size_t)(n0 + arow) * DMODEL + ahalf * 32;
  const unsigned wswz = ((unsigned)(arow & 7)) << 4;
  const unsigned rswz = ((unsigned)(l15 & 7)) << 4;

  f32x4 acc[4][4];
#pragma unroll
  for (int i = 0; i < 4; ++i)
#pragma unroll
    for (int j = 0; j < 4; ++j) acc[i][j] = zero4();

  i32x4 ar4[4];
  f32x4 br8[8];
#pragma unroll
  for (int j = 0; j < 4; ++j) ar4[j] = *(const i32x4*)(Ag + j * 8);
#pragma unroll
  for (int j = 0; j < 8; ++j) br8[j] = *(const f32x4*)(Bg + j * 4);

  for (int kt = 0; kt < 16; ++kt) {
    __syncthreads();
#pragma unroll
    for (int j = 0; j < 4; ++j) {
      i32x4 wb;
      wb[0] = (int)pk(br8[2*j][0], br8[2*j][1]);
      wb[1] = (int)pk(br8[2*j][2], br8[2*j][3]);
      wb[2] = (int)pk(br8[2*j+1][0], br8[2*j+1][1]);
      wb[3] = (int)pk(br8[2*j+1][2], br8[2*j+1][3]);
      const unsigned off = (unsigned)(arow * 128) + (((unsigned)(ahalf * 64 + j * 16)) ^ wswz);
      *(i32x4*)(Al + off) = ar4[j];
      *(i32x4*)(Bl + off) = wb;
    }
    __syncthreads();
    if (kt < 15) {
      const unsigned short* Ap = Ag + (kt + 1) * 64;
      const float* Bp = Bg + (kt + 1) * 64;
#pragma unroll
      for (int j = 0; j < 4; ++j) ar4[j] = *(const i32x4*)(Ap + j * 8);
#pragma unroll
      for (int j = 0; j < 8; ++j) br8[j] = *(const f32x4*)(Bp + j * 4);
    }
#pragma unroll
    for (int kh = 0; kh < 2; ++kh) {
      bf16x8 afr[4], bfr[4];
      const unsigned cb = ((unsigned)(kh * 64 + g * 16)) ^ rswz;
#pragma unroll
      for (int i = 0; i < 4; ++i) {
        afr[i] = *(const bf16x8*)(Al + (wr * 64 + i * 16 + l15) * 128 + cb);
        bfr[i] = *(const bf16x8*)(Bl + (wc * 64 + i * 16 + l15) * 128 + cb);
      }
#pragma unroll
      for (int mi = 0; mi < 4; ++mi)
#pragma unroll
        for (int ni = 0; ni < 4; ++ni)
          acc[mi][ni] = __builtin_amdgcn_mfma_f32_16x16x32_bf16(
              afr[mi], bfr[ni], acc[mi][ni], 0, 0, 0);
    }
  }

  float bv4[4];
#pragma unroll
  for (int ni = 0; ni < 4; ++ni) bv4[ni] = bo[n0 + wc * 64 + ni * 16 + l15];
#pragma unroll
  for (int mi = 0; mi < 4; ++mi) {
#pragma unroll
    for (int ni = 0; ni < 4; ++ni) {
      const int n = n0 + wc * 64 + ni * 16 + l15;
#pragma unroll
      for (int rr = 0; rr < 4; ++rr) {
        const int m = m0 + wr * 64 + mi * 16 + 4 * g + rr;
        out[(size_t)m * DMODEL + n] = acc[mi][ni][rr] + bv4[ni];
      }
    }
  }
}

// ---------------------------------------------------------------------------
extern "C" void kernel_launch(void* const* d_in, const int* in_sizes, int n_in,
                              void* d_out, int out_size, void* d_ws, size_t ws_size,
                              hipStream_t stream) {
  const float* query = (const float*)d_in[0];
  const float* key_  = (const float*)d_in[1];
  const float* value = (const float*)d_in[2];
  const int*   mask  = (const int*)d_in[3];
  const float* Wq = (const float*)d_in[4];
  const float* bq = (const float*)d_in[5];
  const float* Wk = (const float*)d_in[6];
  const float* bk = (const float*)d_in[7];
  const float* Wv = (const float*)d_in[8];
  const float* bv = (const float*)d_in[9];
  const float* Wo = (const float*)d_in[10];
  const float* bo = (const float*)d_in[11];
  float* out = (float*)d_out;

  char* ws = (char*)d_ws;
  unsigned short* q_ws = (unsigned short*)(ws);
  unsigned short* k_ws = (unsigned short*)(ws + (size_t)16777216);
  unsigned short* vT   = (unsigned short*)(ws + (size_t)2 * 16777216);
  unsigned short* o_ws = (unsigned short*)(ws + (size_t)3 * 16777216);

  gemm_qkv<<<dim3(1536), 256, 0, stream>>>(query, key_, value,
                                           Wq, bq, Wk, bk, Wv, bv,
                                           q_ws, k_ws, vT);
  attn<<<dim3(64, 16), 256, 0, stream>>>(q_ws, k_ws, vT, mask, o_ws);
  gemm_out<<<dim3(512), 256, 0, stream>>>(o_ws, Wo, bo, out);
}

// Round 4
// 302.539 us; speedup vs baseline: 1.2869x; 1.2869x over previous
//
#include <hip/hip_runtime.h>

// MultiHeadedAttention: B=4, S=2048, H=16, D_K=64, D_MODEL=1024
// Pipeline: [gemm_qkv] -> [flash attn] -> [gemm_out]
// ws layout (64 MiB):
//   q_ws [64][2048][64] bf16 @ 0      (16 MiB)  (pre-scaled by 0.125*log2e)
//   k_ws [64][2048][64] bf16 @ 16MiB  (16 MiB)
//   vT   [64][64][2048] bf16 @ 32MiB  (16 MiB)  (V^T per head: [bh][d][s])
//   o_ws [4][2048][1024] bf16 @ 48MiB (16 MiB)

#define DMODEL 1024
#define SLEN 2048
#define NHEAD 16
#define LOG2E 1.44269504088896340736f

typedef __attribute__((ext_vector_type(4))) float f32x4;
typedef __attribute__((ext_vector_type(8))) short bf16x8;
typedef __attribute__((ext_vector_type(4))) int i32x4;
typedef __attribute__((ext_vector_type(2))) int i32x2;

__device__ __forceinline__ unsigned short f2bf(float f) {
  __bf16 h = (__bf16)f;
  union { __bf16 h; unsigned short u; } cv; cv.h = h; return cv.u;
}
__device__ __forceinline__ unsigned pk(float a, float b) {
  return (unsigned)f2bf(a) | ((unsigned)f2bf(b) << 16);
}
__device__ __forceinline__ float fexp2(float x) {
  return exp2f(x);
}
__device__ __forceinline__ f32x4 zero4() {
  f32x4 z; z[0] = 0.f; z[1] = 0.f; z[2] = 0.f; z[3] = 0.f; return z;
}
// async global->LDS, 16B per lane; lds dest wave-uniform base + lane*16
__device__ __forceinline__ void gload16(const void* g, void* l) {
  __builtin_amdgcn_global_load_lds(
      (const __attribute__((address_space(1))) unsigned int*)(uintptr_t)g,
      (__attribute__((address_space(3))) unsigned int*)(uintptr_t)l, 16, 0, 0);
}

// ---------------------------------------------------------------------------
// QKV projection: Y = X @ W^T + b ; M=8192,N=1024,K=1024 per z; out bf16
// per-head layout. BK=32. A staged as raw fp32 via async global_load_lds
// (swizzled source, chunk c^(r&7) on 128B rows), converted to bf16 at
// fragment-read. B reg-staged to bf16 LDS (64B rows, chunk c^((r>>1)&3)).
// ONE __syncthreads per K-step. T1 XCD-chunked grid. z==2: V^T epilogue.
// ---------------------------------------------------------------------------
__global__ __launch_bounds__(256)
void gemm_qkv(const float* __restrict__ xq, const float* __restrict__ xk,
              const float* __restrict__ xv,
              const float* __restrict__ Wq, const float* __restrict__ bq,
              const float* __restrict__ Wk, const float* __restrict__ bk,
              const float* __restrict__ Wv, const float* __restrict__ bv,
              unsigned short* __restrict__ qw, unsigned short* __restrict__ kw,
              unsigned short* __restrict__ vw)
{
  // T1: XCD-chunked bijective remap (1536 = 8 * 192), n fastest within chunk
  const int bid = blockIdx.x;
  const int wg = (bid & 7) * 192 + (bid >> 3);
  const int z = wg >> 9;
  const int r = wg & 511;
  const int m0 = (r >> 3) * 128;
  const int n0 = (r & 7) * 128;

  const float* __restrict__ X    = (z == 0) ? xq : (z == 1) ? xk : xv;
  const float* __restrict__ W    = (z == 0) ? Wq : (z == 1) ? Wk : Wv;
  const float* __restrict__ bias = (z == 0) ? bq : (z == 1) ? bk : bv;
  const float scale = (z == 0) ? 0.125f * LOG2E : 1.0f;

  const int tid = threadIdx.x;
  const int lane = tid & 63, wid = tid >> 6;
  const int l15 = lane & 15, g = lane >> 4;
  const int wr = wid >> 1, wc = wid & 1;

  // LDS: A fp32 2x16KB @0, B bf16 2x8KB @32768  (48 KB)
  __shared__ __align__(16) char LDS[49152];
  unsigned short* TT = (unsigned short*)LDS;   // epilogue overlay [64][136]

  // ---- A async staging: 4 rounds/tile, row = rho*32 + (tid>>3), chunk tid&7
  const int arow_g = tid >> 3;                 // 0..31
  const int ac = tid & 7;
  const float* Abase = X + (size_t)(m0 + arow_g) * DMODEL + (ac ^ (arow_g & 7)) * 4;

  // ---- B reg staging: row = tid>>1, k-half = tid&1 (16 fp32)
  const int srow = tid >> 1, sh = tid & 1;
  const float* __restrict__ Bg = W + (size_t)(n0 + srow) * DMODEL + sh * 16;
  const unsigned bw0 = (unsigned)(srow * 64) + (((unsigned)(sh * 2))     ^ ((unsigned)((srow >> 1) & 3))) * 16;
  const unsigned bw1 = (unsigned)(srow * 64) + (((unsigned)(sh * 2 + 1)) ^ ((unsigned)((srow >> 1) & 3))) * 16;

  auto stageA = [&](int kt2, int bufsel) {
    char* dst = LDS + bufsel * 16384 + wid * 1024;
    const float* src = Abase + kt2 * 32;
#pragma unroll
    for (int rho = 0; rho < 4; ++rho)
      gload16(src + (size_t)rho * 32 * DMODEL, dst + rho * 4096);
  };

  f32x4 br4[4];
  auto loadB = [&](int kt2) {
    const float* p = Bg + kt2 * 32;
#pragma unroll
    for (int j = 0; j < 4; ++j) br4[j] = *(const f32x4*)(p + j * 4);
  };
  auto packB = [&](int bufsel) {
    char* Bb = LDS + 32768 + bufsel * 8192;
    i32x4 wv0, wv1;
    wv0[0] = (int)pk(br4[0][0], br4[0][1]); wv0[1] = (int)pk(br4[0][2], br4[0][3]);
    wv0[2] = (int)pk(br4[1][0], br4[1][1]); wv0[3] = (int)pk(br4[1][2], br4[1][3]);
    wv1[0] = (int)pk(br4[2][0], br4[2][1]); wv1[1] = (int)pk(br4[2][2], br4[2][3]);
    wv1[2] = (int)pk(br4[3][0], br4[3][1]); wv1[3] = (int)pk(br4[3][2], br4[3][3]);
    *(i32x4*)(Bb + bw0) = wv0;
    *(i32x4*)(Bb + bw1) = wv1;
  };

  f32x4 acc[4][4];
#pragma unroll
  for (int i = 0; i < 4; ++i)
#pragma unroll
    for (int j = 0; j < 4; ++j) acc[i][j] = zero4();

  // prologue: stage tile 0
  stageA(0, 0);
  loadB(0);
  packB(0);
  loadB(1);
  __syncthreads();

  for (int kt = 0; kt < 32; ++kt) {
    const int cur = kt & 1;
    if (kt + 1 < 32) {
      stageA(kt + 1, cur ^ 1);
      packB(cur ^ 1);              // br4 holds tile kt+1
    }
    if (kt + 2 < 32) loadB(kt + 2);

    // ---- fragments from LDS ----
    const char* Ab = LDS + cur * 16384;
    const char* Bb = LDS + 32768 + cur * 8192;
    bf16x8 afr[4], bfr[4];
#pragma unroll
    for (int i = 0; i < 4; ++i) {
      const int ra = wr * 64 + i * 16 + l15;
      const char* rbase = Ab + ra * 128;
      const int c0 = (2 * g) ^ (ra & 7);
      const int c1 = (2 * g + 1) ^ (ra & 7);
      const f32x4 va = *(const f32x4*)(rbase + c0 * 16);
      const f32x4 vb = *(const f32x4*)(rbase + c1 * 16);
      i32x4 t;
      t[0] = (int)pk(va[0], va[1]); t[1] = (int)pk(va[2], va[3]);
      t[2] = (int)pk(vb[0], vb[1]); t[3] = (int)pk(vb[2], vb[3]);
      union { i32x4 i; bf16x8 h; } u; u.i = t; afr[i] = u.h;

      const int rb = wc * 64 + i * 16 + l15;
      bfr[i] = *(const bf16x8*)(Bb + rb * 64 + ((g ^ ((rb >> 1) & 3)) * 16));
    }
#pragma unroll
    for (int mi = 0; mi < 4; ++mi)
#pragma unroll
      for (int ni = 0; ni < 4; ++ni)
        acc[mi][ni] = __builtin_amdgcn_mfma_f32_16x16x32_bf16(
            afr[mi], bfr[ni], acc[mi][ni], 0, 0, 0);

    if (kt + 1 < 32) __syncthreads();
  }

  float bv4[4];
#pragma unroll
  for (int ni = 0; ni < 4; ++ni) bv4[ni] = bias[n0 + wc * 64 + ni * 16 + l15];

  if (z == 2) {
    // ---- transpose epilogue: store V^T [b*1024 + n][s] ----
    const int bb = m0 >> 11, s0 = m0 & 2047;
#pragma unroll
    for (int p = 0; p < 2; ++p) {
      __syncthreads();
      if (wc == p) {
#pragma unroll
        for (int mi = 0; mi < 4; ++mi)
#pragma unroll
          for (int ni = 0; ni < 4; ++ni)
#pragma unroll
            for (int rr2 = 0; rr2 < 4; ++rr2)
              TT[(ni * 16 + l15) * 136 + wr * 64 + mi * 16 + 4 * g + rr2] =
                  f2bf(acc[mi][ni][rr2] + bv4[ni]);
      }
      __syncthreads();
      const int rr = tid >> 2, cc = (tid & 3) * 32;
      unsigned short* dp = vw + ((size_t)(bb * 1024 + n0 + p * 64 + rr)) * 2048 + s0 + cc;
      const unsigned short* sp = &TT[rr * 136 + cc];
#pragma unroll
      for (int j = 0; j < 4; ++j)
        *(i32x4*)(void*)(dp + j * 8) = *(const i32x4*)(const void*)(sp + j * 8);
    }
    return;
  }

  unsigned short* __restrict__ dst = (z == 0) ? qw : kw;
#pragma unroll
  for (int mi = 0; mi < 4; ++mi) {
#pragma unroll
    for (int ni = 0; ni < 4; ++ni) {
      const int n = n0 + wc * 64 + ni * 16 + l15;
      const int h = n >> 6, d = n & 63;
#pragma unroll
      for (int rr2 = 0; rr2 < 4; ++rr2) {
        const int m = m0 + wr * 64 + mi * 16 + 4 * g + rr2;
        const int b = m >> 11, s = m & 2047;
        const float val = (acc[mi][ni][rr2] + bv4[ni]) * scale;
        dst[((size_t)(b * NHEAD + h) * SLEN + s) * 64 + d] = f2bf(val);
      }
    }
  }
}

// ---------------------------------------------------------------------------
// Flash attention. 4 waves x 32 q-rows (QBLK 128). KVBLK 64, double-buffered
// global_load_lds staging with XOR-swizzled source; exp2-domain online softmax
// with defer-max; mask folded into MFMA C-init.  (unchanged)
// ---------------------------------------------------------------------------
__global__ __launch_bounds__(256, 3)
void attn(const unsigned short* __restrict__ q_ws,
          const unsigned short* __restrict__ k_ws,
          const unsigned short* __restrict__ vT,
          const int* __restrict__ mask,
          unsigned short* __restrict__ o_ws)
{
  const int bh = blockIdx.x;            // 0..63
  const int qt = blockIdx.y;            // 0..15
  const int b = bh >> 4, h = bh & 15;
  const int tid = threadIdx.x, w = tid >> 6, lane = tid & 63;
  const int l15 = lane & 15, g = lane >> 4;

  __shared__ __align__(16) unsigned short Kb[2][64 * 64];
  __shared__ __align__(16) unsigned short Vb[2][64 * 64];
  __shared__ __align__(16) unsigned short Pl[4][16 * 64];
  __shared__ __align__(16) float maskf[2048];

  {
    const int4* mp = (const int4*)(mask + b * SLEN);
    const int4 ma = mp[tid * 2], mb = mp[tid * 2 + 1];
    float4 f0, f1;
    f0.x = ma.x ? 0.f : -1e9f; f0.y = ma.y ? 0.f : -1e9f;
    f0.z = ma.z ? 0.f : -1e9f; f0.w = ma.w ? 0.f : -1e9f;
    f1.x = mb.x ? 0.f : -1e9f; f1.y = mb.y ? 0.f : -1e9f;
    f1.z = mb.z ? 0.f : -1e9f; f1.w = mb.w ? 0.f : -1e9f;
    *(float4*)&maskf[tid * 8]     = f0;
    *(float4*)&maskf[tid * 8 + 4] = f1;
  }

  const size_t head = (size_t)bh * SLEN;
  const int r8 = lane >> 3, c8 = lane & 7;
  const int swz = ((c8 ^ r8) * 16);
  const unsigned pswz = (unsigned)((l15 & 7) << 4);

  const int qbase = qt * 128 + w * 32;
  bf16x8 qf[2][2];
  {
    const unsigned short* qp0 = q_ws + (head + qbase + l15) * 64;
    const unsigned short* qp1 = q_ws + (head + qbase + 16 + l15) * 64;
    qf[0][0] = *(const bf16x8*)(qp0 + g * 8);
    qf[0][1] = *(const bf16x8*)(qp0 + 32 + g * 8);
    qf[1][0] = *(const bf16x8*)(qp1 + g * 8);
    qf[1][1] = *(const bf16x8*)(qp1 + 32 + g * 8);
  }

  auto stage = [&](int kt2, int bufi) {
#pragma unroll
    for (int cl = 0; cl < 2; ++cl) {
      const int rr = w * 16 + cl * 8 + r8;
      const char* gk = (const char*)(k_ws + (head + kt2 * 64 + rr) * 64) + swz;
      gload16(gk, &Kb[bufi][(w * 16 + cl * 8) * 64]);
      const char* gv = (const char*)(vT + ((size_t)(bh * 64 + rr)) * SLEN + kt2 * 64) + swz;
      gload16(gv, &Vb[bufi][(w * 16 + cl * 8) * 64]);
    }
  };

  stage(0, 0);
  __syncthreads();

  float m_run[2] = {-1e30f, -1e30f};
  float l_run[2] = {0.f, 0.f};
  f32x4 of[2][4];
#pragma unroll
  for (int qi = 0; qi < 2; ++qi)
#pragma unroll
    for (int n = 0; n < 4; ++n) of[qi][n] = zero4();

  unsigned short* Pw = (unsigned short*)Pl[w];
  int cur = 0;

  for (int kt = 0; kt < 32; ++kt) {
    if (kt + 1 < 32) stage(kt + 1, cur ^ 1);
    const char* Kc = (const char*)Kb[cur];
    const char* Vc = (const char*)Vb[cur];
    const int kv0 = kt * 64;

    f32x4 mv[4];
#pragma unroll
    for (int s = 0; s < 4; ++s) mv[s] = *(const f32x4*)&maskf[kv0 + s * 16 + g * 4];

#pragma unroll
    for (int qi = 0; qi < 2; ++qi) {
      f32x4 sac[4];
#pragma unroll
      for (int s = 0; s < 4; ++s) {
        const char* kr = Kc + (s * 16 + l15) * 128;
        const bf16x8 kf0 = *(const bf16x8*)(kr + ((unsigned)(g * 16) ^ pswz));
        const bf16x8 kf1 = *(const bf16x8*)(kr + ((unsigned)(64 + g * 16) ^ pswz));
        f32x4 zt = mv[s];
        zt = __builtin_amdgcn_mfma_f32_16x16x32_bf16(kf0, qf[qi][0], zt, 0, 0, 0);
        sac[s] = __builtin_amdgcn_mfma_f32_16x16x32_bf16(kf1, qf[qi][1], zt, 0, 0, 0);
      }

      float tmax = -3.0e38f;
#pragma unroll
      for (int s = 0; s < 4; ++s)
#pragma unroll
        for (int rr = 0; rr < 4; ++rr) tmax = fmaxf(tmax, sac[s][rr]);
      tmax = fmaxf(tmax, __shfl_xor(tmax, 16));
      tmax = fmaxf(tmax, __shfl_xor(tmax, 32));
      if (!__all(tmax <= m_run[qi] + 8.f)) {
        const float mnew = fmaxf(m_run[qi], tmax);
        const float alpha = fexp2(m_run[qi] - mnew);
        float af[4];
#pragma unroll
        for (int rr = 0; rr < 4; ++rr) af[rr] = __shfl(alpha, g * 4 + rr);
#pragma unroll
        for (int n = 0; n < 4; ++n)
#pragma unroll
          for (int rr = 0; rr < 4; ++rr) of[qi][n][rr] *= af[rr];
        l_run[qi] *= alpha;
        m_run[qi] = mnew;
      }
      float psum = 0.f;
      unsigned pr[4][2];
#pragma unroll
      for (int s = 0; s < 4; ++s) {
        const float p0 = fexp2(sac[s][0] - m_run[qi]);
        const float p1 = fexp2(sac[s][1] - m_run[qi]);
        const float p2 = fexp2(sac[s][2] - m_run[qi]);
        const float p3 = fexp2(sac[s][3] - m_run[qi]);
        psum += (p0 + p1) + (p2 + p3);
        pr[s][0] = pk(p0, p1); pr[s][1] = pk(p2, p3);
      }
      l_run[qi] += psum;
#pragma unroll
      for (int s = 0; s < 4; ++s) {
        i32x2 wv; wv[0] = (int)pr[s][0]; wv[1] = (int)pr[s][1];
        *(i32x2*)(void*)((char*)Pw + l15 * 128 + ((unsigned)(s * 32 + g * 8) ^ pswz)) = wv;
      }

#pragma unroll
      for (int k2 = 0; k2 < 2; ++k2) {
        const bf16x8 pa = *(const bf16x8*)(const void*)(
            (const char*)Pw + l15 * 128 + ((unsigned)(k2 * 64 + g * 16) ^ pswz));
#pragma unroll
        for (int n = 0; n < 4; ++n) {
          const bf16x8 vf = *(const bf16x8*)(
              Vc + (n * 16 + l15) * 128 + ((unsigned)(k2 * 64 + g * 16) ^ pswz));
          of[qi][n] = __builtin_amdgcn_mfma_f32_16x16x32_bf16(pa, vf, of[qi][n], 0, 0, 0);
        }
      }
    }
    __syncthreads();
    cur ^= 1;
  }

#pragma unroll
  for (int qi = 0; qi < 2; ++qi) {
    float lt = l_run[qi];
    lt += __shfl_xor(lt, 16);
    lt += __shfl_xor(lt, 32);
    float inv[4];
#pragma unroll
    for (int rr = 0; rr < 4; ++rr) inv[rr] = 1.f / __shfl(lt, g * 4 + rr);
    const int qrow0 = qt * 128 + w * 32 + qi * 16;
#pragma unroll
    for (int n = 0; n < 4; ++n) {
      const int d = h * 64 + n * 16 + l15;
#pragma unroll
      for (int rr = 0; rr < 4; ++rr) {
        const int sr = qrow0 + 4 * g + rr;
        o_ws[((size_t)b * SLEN + sr) * DMODEL + d] = f2bf(of[qi][n][rr] * inv[rr]);
      }
    }
  }
}

// ---------------------------------------------------------------------------
// Output projection: out = O @ Wo^T + bo (fp32 out). A (o_ws) already bf16 ->
// direct async gload (64B rows, chunk c^((r>>1)&3)). B reg-staged. One
// barrier per K-step. T1 remap.
// ---------------------------------------------------------------------------
__global__ __launch_bounds__(256)
void gemm_out(const unsigned short* __restrict__ ow,
              const float* __restrict__ Wo, const float* __restrict__ bo,
              float* __restrict__ out)
{
  const int bid = blockIdx.x;                      // 512 = 8 * 64
  const int wg = (bid & 7) * 64 + (bid >> 3);
  const int m0 = (wg >> 3) * 128;
  const int n0 = (wg & 7) * 128;

  const int tid = threadIdx.x;
  const int lane = tid & 63, wid = tid >> 6;
  const int l15 = lane & 15, g = lane >> 4;
  const int wr = wid >> 1, wc = wid & 1;

  // LDS: A bf16 2x8KB @0, B bf16 2x8KB @16384 (32 KB)
  __shared__ __align__(16) char LDS[32768];

  // A async staging: 2 rounds/tile, row = rho*64 + (tid>>2), chunk tid&3
  const int arow = tid >> 2;                // 0..63
  const int ac = tid & 3;
  const unsigned short* Abase = ow + (size_t)(m0 + arow) * DMODEL
                                 + (ac ^ ((arow >> 1) & 3)) * 8;

  const int srow = tid >> 1, sh = tid & 1;
  const float* __restrict__ Bg = Wo + (size_t)(n0 + srow) * DMODEL + sh * 16;
  const unsigned bw0 = (unsigned)(srow * 64) + (((unsigned)(sh * 2))     ^ ((unsigned)((srow >> 1) & 3))) * 16;
  const unsigned bw1 = (unsigned)(srow * 64) + (((unsigned)(sh * 2 + 1)) ^ ((unsigned)((srow >> 1) & 3))) * 16;

  auto stageA = [&](int kt2, int bufsel) {
    char* dst = LDS + bufsel * 8192 + wid * 1024;
    const unsigned short* src = Abase + kt2 * 32;
#pragma unroll
    for (int rho = 0; rho < 2; ++rho)
      gload16(src + (size_t)rho * 64 * DMODEL, dst + rho * 4096);
  };

  f32x4 br4[4];
  auto loadB = [&](int kt2) {
    const float* p = Bg + kt2 * 32;
#pragma unroll
    for (int j = 0; j < 4; ++j) br4[j] = *(const f32x4*)(p + j * 4);
  };
  auto packB = [&](int bufsel) {
    char* Bb = LDS + 16384 + bufsel * 8192;
    i32x4 wv0, wv1;
    wv0[0] = (int)pk(br4[0][0], br4[0][1]); wv0[1] = (int)pk(br4[0][2], br4[0][3]);
    wv0[2] = (int)pk(br4[1][0], br4[1][1]); wv0[3] = (int)pk(br4[1][2], br4[1][3]);
    wv1[0] = (int)pk(br4[2][0], br4[2][1]); wv1[1] = (int)pk(br4[2][2], br4[2][3]);
    wv1[2] = (int)pk(br4[3][0], br4[3][1]); wv1[3] = (int)pk(br4[3][2], br4[3][3]);
    *(i32x4*)(Bb + bw0) = wv0;
    *(i32x4*)(Bb + bw1) = wv1;
  };

  f32x4 acc[4][4];
#pragma unroll
  for (int i = 0; i < 4; ++i)
#pragma unroll
    for (int j = 0; j < 4; ++j) acc[i][j] = zero4();

  stageA(0, 0);
  loadB(0);
  packB(0);
  loadB(1);
  __syncthreads();

  for (int kt = 0; kt < 32; ++kt) {
    const int cur = kt & 1;
    if (kt + 1 < 32) {
      stageA(kt + 1, cur ^ 1);
      packB(cur ^ 1);
    }
    if (kt + 2 < 32) loadB(kt + 2);

    const char* Ab = LDS + cur * 8192;
    const char* Bb = LDS + 16384 + cur * 8192;
    bf16x8 afr[4], bfr[4];
#pragma unroll
    for (int i = 0; i < 4; ++i) {
      const int ra = wr * 64 + i * 16 + l15;
      afr[i] = *(const bf16x8*)(Ab + ra * 64 + ((g ^ ((ra >> 1) & 3)) * 16));
      const int rb = wc * 64 + i * 16 + l15;
      bfr[i] = *(const bf16x8*)(Bb + rb * 64 + ((g ^ ((rb >> 1) & 3)) * 16));
    }
#pragma unroll
    for (int mi = 0; mi < 4; ++mi)
#pragma unroll
      for (int ni = 0; ni < 4; ++ni)
        acc[mi][ni] = __builtin_amdgcn_mfma_f32_16x16x32_bf16(
            afr[mi], bfr[ni], acc[mi][ni], 0, 0, 0);

    if (kt + 1 < 32) __syncthreads();
  }

  float bv4[4];
#pragma unroll
  for (int ni = 0; ni < 4; ++ni) bv4[ni] = bo[n0 + wc * 64 + ni * 16 + l15];
#pragma unroll
  for (int mi = 0; mi < 4; ++mi) {
#pragma unroll
    for (int ni = 0; ni < 4; ++ni) {
      const int n = n0 + wc * 64 + ni * 16 + l15;
#pragma unroll
      for (int rr = 0; rr < 4; ++rr) {
        const int m = m0 + wr * 64 + mi * 16 + 4 * g + rr;
        out[(size_t)m * DMODEL + n] = acc[mi][ni][rr] + bv4[ni];
      }
    }
  }
}

// ---------------------------------------------------------------------------
extern "C" void kernel_launch(void* const* d_in, const int* in_sizes, int n_in,
                              void* d_out, int out_size, void* d_ws, size_t ws_size,
                              hipStream_t stream) {
  const float* query = (const float*)d_in[0];
  const float* key_  = (const float*)d_in[1];
  const float* value = (const float*)d_in[2];
  const int*   mask  = (const int*)d_in[3];
  const float* Wq = (const float*)d_in[4];
  const float* bq = (const float*)d_in[5];
  const float* Wk = (const float*)d_in[6];
  const float* bk = (const float*)d_in[7];
  const float* Wv = (const float*)d_in[8];
  const float* bv = (const float*)d_in[9];
  const float* Wo = (const float*)d_in[10];
  const float* bo = (const float*)d_in[11];
  float* out = (float*)d_out;

  char* ws = (char*)d_ws;
  unsigned short* q_ws = (unsigned short*)(ws);
  unsigned short* k_ws = (unsigned short*)(ws + (size_t)16777216);
  unsigned short* vT   = (unsigned short*)(ws + (size_t)2 * 16777216);
  unsigned short* o_ws = (unsigned short*)(ws + (size_t)3 * 16777216);

  gemm_qkv<<<dim3(1536), 256, 0, stream>>>(query, key_, value,
                                           Wq, bq, Wk, bk, Wv, bv,
                                           q_ws, k_ws, vT);
  attn<<<dim3(64, 16), 256, 0, stream>>>(q_ws, k_ws, vT, mask, o_ws);
  gemm_out<<<dim3(512), 256, 0, stream>>>(o_ws, Wo, bo, out);
}

// Round 5
// 275.239 us; speedup vs baseline: 1.4145x; 1.0992x over previous
//
#include <hip/hip_runtime.h>

// MultiHeadedAttention: B=4, S=2048, H=16, D_K=64, D_MODEL=1024
// Pipeline: [gemm_qkv] -> [flash attn] -> [gemm_out]
// ws layout (64 MiB):
//   q_ws [64][2048][64] bf16 @ 0      (16 MiB)  (pre-scaled by 0.125*log2e)
//   k_ws [64][2048][64] bf16 @ 16MiB  (16 MiB)
//   vT   [64][64][2048] bf16 @ 32MiB  (16 MiB)  (V^T per head: [bh][d][s])
//   o_ws [4][2048][1024] bf16 @ 48MiB (16 MiB)

#define DMODEL 1024
#define SLEN 2048
#define NHEAD 16
#define LOG2E 1.44269504088896340736f

typedef __attribute__((ext_vector_type(4))) float f32x4;
typedef __attribute__((ext_vector_type(8))) short bf16x8;
typedef __attribute__((ext_vector_type(4))) int i32x4;
typedef __attribute__((ext_vector_type(2))) int i32x2;

__device__ __forceinline__ unsigned short f2bf(float f) {
  __bf16 h = (__bf16)f;
  union { __bf16 h; unsigned short u; } cv; cv.h = h; return cv.u;
}
__device__ __forceinline__ unsigned pk(float a, float b) {
  return (unsigned)f2bf(a) | ((unsigned)f2bf(b) << 16);
}
// single-instruction hardware exp2 (TRANS pipe). Plain exp2f() without
// fast-math lowers to the OCML denormal-correct sequence (~10 VALU ops)
// and cost attn 2x in R4.
__device__ __forceinline__ float fexp2(float x) {
  float r;
  asm("v_exp_f32 %0, %1" : "=v"(r) : "v"(x));
  return r;
}
__device__ __forceinline__ f32x4 zero4() {
  f32x4 z; z[0] = 0.f; z[1] = 0.f; z[2] = 0.f; z[3] = 0.f; return z;
}
// async global->LDS, 16B per lane; lds dest wave-uniform base + lane*16
__device__ __forceinline__ void gload16(const void* g, void* l) {
  __builtin_amdgcn_global_load_lds(
      (const __attribute__((address_space(1))) unsigned int*)(uintptr_t)g,
      (__attribute__((address_space(3))) unsigned int*)(uintptr_t)l, 16, 0, 0);
}

// ---------------------------------------------------------------------------
// QKV projection: Y = X @ W^T + b ; M=8192,N=1024,K=1024 per z; out bf16
// per-head layout. BK=32. A staged as raw fp32 via async global_load_lds
// (swizzled source, chunk c^(r&7) on 128B rows), converted to bf16 at
// fragment-read. B reg-staged to bf16 LDS (64B rows, chunk c^((r>>1)&3)).
// ONE __syncthreads per K-step. T1 XCD-chunked grid. z==2: V^T epilogue.
// ---------------------------------------------------------------------------
__global__ __launch_bounds__(256)
void gemm_qkv(const float* __restrict__ xq, const float* __restrict__ xk,
              const float* __restrict__ xv,
              const float* __restrict__ Wq, const float* __restrict__ bq,
              const float* __restrict__ Wk, const float* __restrict__ bk,
              const float* __restrict__ Wv, const float* __restrict__ bv,
              unsigned short* __restrict__ qw, unsigned short* __restrict__ kw,
              unsigned short* __restrict__ vw)
{
  // T1: XCD-chunked bijective remap (1536 = 8 * 192), n fastest within chunk
  const int bid = blockIdx.x;
  const int wg = (bid & 7) * 192 + (bid >> 3);
  const int z = wg >> 9;
  const int r = wg & 511;
  const int m0 = (r >> 3) * 128;
  const int n0 = (r & 7) * 128;

  const float* __restrict__ X    = (z == 0) ? xq : (z == 1) ? xk : xv;
  const float* __restrict__ W    = (z == 0) ? Wq : (z == 1) ? Wk : Wv;
  const float* __restrict__ bias = (z == 0) ? bq : (z == 1) ? bk : bv;
  const float scale = (z == 0) ? 0.125f * LOG2E : 1.0f;

  const int tid = threadIdx.x;
  const int lane = tid & 63, wid = tid >> 6;
  const int l15 = lane & 15, g = lane >> 4;
  const int wr = wid >> 1, wc = wid & 1;

  // LDS: A fp32 2x16KB @0, B bf16 2x8KB @32768  (48 KB)
  __shared__ __align__(16) char LDS[49152];
  unsigned short* TT = (unsigned short*)LDS;   // epilogue overlay [64][136]

  // ---- A async staging: 4 rounds/tile, row = rho*32 + (tid>>3), chunk tid&7
  const int arow_g = tid >> 3;                 // 0..31
  const int ac = tid & 7;
  const float* Abase = X + (size_t)(m0 + arow_g) * DMODEL + (ac ^ (arow_g & 7)) * 4;

  // ---- B reg staging: row = tid>>1, k-half = tid&1 (16 fp32)
  const int srow = tid >> 1, sh = tid & 1;
  const float* __restrict__ Bg = W + (size_t)(n0 + srow) * DMODEL + sh * 16;
  const unsigned bw0 = (unsigned)(srow * 64) + (((unsigned)(sh * 2))     ^ ((unsigned)((srow >> 1) & 3))) * 16;
  const unsigned bw1 = (unsigned)(srow * 64) + (((unsigned)(sh * 2 + 1)) ^ ((unsigned)((srow >> 1) & 3))) * 16;

  auto stageA = [&](int kt2, int bufsel) {
    char* dst = LDS + bufsel * 16384 + wid * 1024;
    const float* src = Abase + kt2 * 32;
#pragma unroll
    for (int rho = 0; rho < 4; ++rho)
      gload16(src + (size_t)rho * 32 * DMODEL, dst + rho * 4096);
  };

  f32x4 br4[4];
  auto loadB = [&](int kt2) {
    const float* p = Bg + kt2 * 32;
#pragma unroll
    for (int j = 0; j < 4; ++j) br4[j] = *(const f32x4*)(p + j * 4);
  };
  auto packB = [&](int bufsel) {
    char* Bb = LDS + 32768 + bufsel * 8192;
    i32x4 wv0, wv1;
    wv0[0] = (int)pk(br4[0][0], br4[0][1]); wv0[1] = (int)pk(br4[0][2], br4[0][3]);
    wv0[2] = (int)pk(br4[1][0], br4[1][1]); wv0[3] = (int)pk(br4[1][2], br4[1][3]);
    wv1[0] = (int)pk(br4[2][0], br4[2][1]); wv1[1] = (int)pk(br4[2][2], br4[2][3]);
    wv1[2] = (int)pk(br4[3][0], br4[3][1]); wv1[3] = (int)pk(br4[3][2], br4[3][3]);
    *(i32x4*)(Bb + bw0) = wv0;
    *(i32x4*)(Bb + bw1) = wv1;
  };

  f32x4 acc[4][4];
#pragma unroll
  for (int i = 0; i < 4; ++i)
#pragma unroll
    for (int j = 0; j < 4; ++j) acc[i][j] = zero4();

  // prologue: stage tile 0
  stageA(0, 0);
  loadB(0);
  packB(0);
  loadB(1);
  __syncthreads();

  for (int kt = 0; kt < 32; ++kt) {
    const int cur = kt & 1;
    if (kt + 1 < 32) {
      stageA(kt + 1, cur ^ 1);
      packB(cur ^ 1);              // br4 holds tile kt+1
    }
    if (kt + 2 < 32) loadB(kt + 2);

    // ---- fragments from LDS ----
    const char* Ab = LDS + cur * 16384;
    const char* Bb = LDS + 32768 + cur * 8192;
    bf16x8 afr[4], bfr[4];
#pragma unroll
    for (int i = 0; i < 4; ++i) {
      const int ra = wr * 64 + i * 16 + l15;
      const char* rbase = Ab + ra * 128;
      const int c0 = (2 * g) ^ (ra & 7);
      const int c1 = (2 * g + 1) ^ (ra & 7);
      const f32x4 va = *(const f32x4*)(rbase + c0 * 16);
      const f32x4 vb = *(const f32x4*)(rbase + c1 * 16);
      i32x4 t;
      t[0] = (int)pk(va[0], va[1]); t[1] = (int)pk(va[2], va[3]);
      t[2] = (int)pk(vb[0], vb[1]); t[3] = (int)pk(vb[2], vb[3]);
      union { i32x4 i; bf16x8 h; } u; u.i = t; afr[i] = u.h;

      const int rb = wc * 64 + i * 16 + l15;
      bfr[i] = *(const bf16x8*)(Bb + rb * 64 + ((g ^ ((rb >> 1) & 3)) * 16));
    }
#pragma unroll
    for (int mi = 0; mi < 4; ++mi)
#pragma unroll
      for (int ni = 0; ni < 4; ++ni)
        acc[mi][ni] = __builtin_amdgcn_mfma_f32_16x16x32_bf16(
            afr[mi], bfr[ni], acc[mi][ni], 0, 0, 0);

    if (kt + 1 < 32) __syncthreads();
  }

  float bv4[4];
#pragma unroll
  for (int ni = 0; ni < 4; ++ni) bv4[ni] = bias[n0 + wc * 64 + ni * 16 + l15];

  if (z == 2) {
    // ---- transpose epilogue: store V^T [b*1024 + n][s] ----
    const int bb = m0 >> 11, s0 = m0 & 2047;
#pragma unroll
    for (int p = 0; p < 2; ++p) {
      __syncthreads();
      if (wc == p) {
#pragma unroll
        for (int mi = 0; mi < 4; ++mi)
#pragma unroll
          for (int ni = 0; ni < 4; ++ni)
#pragma unroll
            for (int rr2 = 0; rr2 < 4; ++rr2)
              TT[(ni * 16 + l15) * 136 + wr * 64 + mi * 16 + 4 * g + rr2] =
                  f2bf(acc[mi][ni][rr2] + bv4[ni]);
      }
      __syncthreads();
      const int rr = tid >> 2, cc = (tid & 3) * 32;
      unsigned short* dp = vw + ((size_t)(bb * 1024 + n0 + p * 64 + rr)) * 2048 + s0 + cc;
      const unsigned short* sp = &TT[rr * 136 + cc];
#pragma unroll
      for (int j = 0; j < 4; ++j)
        *(i32x4*)(void*)(dp + j * 8) = *(const i32x4*)(const void*)(sp + j * 8);
    }
    return;
  }

  unsigned short* __restrict__ dst = (z == 0) ? qw : kw;
#pragma unroll
  for (int mi = 0; mi < 4; ++mi) {
#pragma unroll
    for (int ni = 0; ni < 4; ++ni) {
      const int n = n0 + wc * 64 + ni * 16 + l15;
      const int h = n >> 6, d = n & 63;
#pragma unroll
      for (int rr2 = 0; rr2 < 4; ++rr2) {
        const int m = m0 + wr * 64 + mi * 16 + 4 * g + rr2;
        const int b = m >> 11, s = m & 2047;
        const float val = (acc[mi][ni][rr2] + bv4[ni]) * scale;
        dst[((size_t)(b * NHEAD + h) * SLEN + s) * 64 + d] = f2bf(val);
      }
    }
  }
}

// ---------------------------------------------------------------------------
// Flash attention. 4 waves x 32 q-rows (QBLK 128). KVBLK 64, double-buffered
// global_load_lds staging with XOR-swizzled source; exp2-domain online softmax
// with defer-max; mask folded into MFMA C-init.
// ---------------------------------------------------------------------------
__global__ __launch_bounds__(256, 3)
void attn(const unsigned short* __restrict__ q_ws,
          const unsigned short* __restrict__ k_ws,
          const unsigned short* __restrict__ vT,
          const int* __restrict__ mask,
          unsigned short* __restrict__ o_ws)
{
  const int bh = blockIdx.x;            // 0..63
  const int qt = blockIdx.y;            // 0..15
  const int b = bh >> 4, h = bh & 15;
  const int tid = threadIdx.x, w = tid >> 6, lane = tid & 63;
  const int l15 = lane & 15, g = lane >> 4;

  __shared__ __align__(16) unsigned short Kb[2][64 * 64];
  __shared__ __align__(16) unsigned short Vb[2][64 * 64];
  __shared__ __align__(16) unsigned short Pl[4][16 * 64];
  __shared__ __align__(16) float maskf[2048];

  {
    const int4* mp = (const int4*)(mask + b * SLEN);
    const int4 ma = mp[tid * 2], mb = mp[tid * 2 + 1];
    float4 f0, f1;
    f0.x = ma.x ? 0.f : -1e9f; f0.y = ma.y ? 0.f : -1e9f;
    f0.z = ma.z ? 0.f : -1e9f; f0.w = ma.w ? 0.f : -1e9f;
    f1.x = mb.x ? 0.f : -1e9f; f1.y = mb.y ? 0.f : -1e9f;
    f1.z = mb.z ? 0.f : -1e9f; f1.w = mb.w ? 0.f : -1e9f;
    *(float4*)&maskf[tid * 8]     = f0;
    *(float4*)&maskf[tid * 8 + 4] = f1;
  }

  const size_t head = (size_t)bh * SLEN;
  const int r8 = lane >> 3, c8 = lane & 7;
  const int swz = ((c8 ^ r8) * 16);
  const unsigned pswz = (unsigned)((l15 & 7) << 4);

  const int qbase = qt * 128 + w * 32;
  bf16x8 qf[2][2];
  {
    const unsigned short* qp0 = q_ws + (head + qbase + l15) * 64;
    const unsigned short* qp1 = q_ws + (head + qbase + 16 + l15) * 64;
    qf[0][0] = *(const bf16x8*)(qp0 + g * 8);
    qf[0][1] = *(const bf16x8*)(qp0 + 32 + g * 8);
    qf[1][0] = *(const bf16x8*)(qp1 + g * 8);
    qf[1][1] = *(const bf16x8*)(qp1 + 32 + g * 8);
  }

  auto stage = [&](int kt2, int bufi) {
#pragma unroll
    for (int cl = 0; cl < 2; ++cl) {
      const int rr = w * 16 + cl * 8 + r8;
      const char* gk = (const char*)(k_ws + (head + kt2 * 64 + rr) * 64) + swz;
      gload16(gk, &Kb[bufi][(w * 16 + cl * 8) * 64]);
      const char* gv = (const char*)(vT + ((size_t)(bh * 64 + rr)) * SLEN + kt2 * 64) + swz;
      gload16(gv, &Vb[bufi][(w * 16 + cl * 8) * 64]);
    }
  };

  stage(0, 0);
  __syncthreads();

  float m_run[2] = {-1e30f, -1e30f};
  float l_run[2] = {0.f, 0.f};
  f32x4 of[2][4];
#pragma unroll
  for (int qi = 0; qi < 2; ++qi)
#pragma unroll
    for (int n = 0; n < 4; ++n) of[qi][n] = zero4();

  unsigned short* Pw = (unsigned short*)Pl[w];
  int cur = 0;

  for (int kt = 0; kt < 32; ++kt) {
    if (kt + 1 < 32) stage(kt + 1, cur ^ 1);
    const char* Kc = (const char*)Kb[cur];
    const char* Vc = (const char*)Vb[cur];
    const int kv0 = kt * 64;

    f32x4 mv[4];
#pragma unroll
    for (int s = 0; s < 4; ++s) mv[s] = *(const f32x4*)&maskf[kv0 + s * 16 + g * 4];

#pragma unroll
    for (int qi = 0; qi < 2; ++qi) {
      f32x4 sac[4];
#pragma unroll
      for (int s = 0; s < 4; ++s) {
        const char* kr = Kc + (s * 16 + l15) * 128;
        const bf16x8 kf0 = *(const bf16x8*)(kr + ((unsigned)(g * 16) ^ pswz));
        const bf16x8 kf1 = *(const bf16x8*)(kr + ((unsigned)(64 + g * 16) ^ pswz));
        f32x4 zt = mv[s];
        zt = __builtin_amdgcn_mfma_f32_16x16x32_bf16(kf0, qf[qi][0], zt, 0, 0, 0);
        sac[s] = __builtin_amdgcn_mfma_f32_16x16x32_bf16(kf1, qf[qi][1], zt, 0, 0, 0);
      }

      float tmax = -3.0e38f;
#pragma unroll
      for (int s = 0; s < 4; ++s)
#pragma unroll
        for (int rr = 0; rr < 4; ++rr) tmax = fmaxf(tmax, sac[s][rr]);
      tmax = fmaxf(tmax, __shfl_xor(tmax, 16));
      tmax = fmaxf(tmax, __shfl_xor(tmax, 32));
      if (!__all(tmax <= m_run[qi] + 8.f)) {
        const float mnew = fmaxf(m_run[qi], tmax);
        const float alpha = fexp2(m_run[qi] - mnew);
        float af[4];
#pragma unroll
        for (int rr = 0; rr < 4; ++rr) af[rr] = __shfl(alpha, g * 4 + rr);
#pragma unroll
        for (int n = 0; n < 4; ++n)
#pragma unroll
          for (int rr = 0; rr < 4; ++rr) of[qi][n][rr] *= af[rr];
        l_run[qi] *= alpha;
        m_run[qi] = mnew;
      }
      float psum = 0.f;
      unsigned pr[4][2];
#pragma unroll
      for (int s = 0; s < 4; ++s) {
        const float p0 = fexp2(sac[s][0] - m_run[qi]);
        const float p1 = fexp2(sac[s][1] - m_run[qi]);
        const float p2 = fexp2(sac[s][2] - m_run[qi]);
        const float p3 = fexp2(sac[s][3] - m_run[qi]);
        psum += (p0 + p1) + (p2 + p3);
        pr[s][0] = pk(p0, p1); pr[s][1] = pk(p2, p3);
      }
      l_run[qi] += psum;
#pragma unroll
      for (int s = 0; s < 4; ++s) {
        i32x2 wv; wv[0] = (int)pr[s][0]; wv[1] = (int)pr[s][1];
        *(i32x2*)(void*)((char*)Pw + l15 * 128 + ((unsigned)(s * 32 + g * 8) ^ pswz)) = wv;
      }

#pragma unroll
      for (int k2 = 0; k2 < 2; ++k2) {
        const bf16x8 pa = *(const bf16x8*)(const void*)(
            (const char*)Pw + l15 * 128 + ((unsigned)(k2 * 64 + g * 16) ^ pswz));
#pragma unroll
        for (int n = 0; n < 4; ++n) {
          const bf16x8 vf = *(const bf16x8*)(
              Vc + (n * 16 + l15) * 128 + ((unsigned)(k2 * 64 + g * 16) ^ pswz));
          of[qi][n] = __builtin_amdgcn_mfma_f32_16x16x32_bf16(pa, vf, of[qi][n], 0, 0, 0);
        }
      }
    }
    __syncthreads();
    cur ^= 1;
  }

#pragma unroll
  for (int qi = 0; qi < 2; ++qi) {
    float lt = l_run[qi];
    lt += __shfl_xor(lt, 16);
    lt += __shfl_xor(lt, 32);
    float inv[4];
#pragma unroll
    for (int rr = 0; rr < 4; ++rr) inv[rr] = 1.f / __shfl(lt, g * 4 + rr);
    const int qrow0 = qt * 128 + w * 32 + qi * 16;
#pragma unroll
    for (int n = 0; n < 4; ++n) {
      const int d = h * 64 + n * 16 + l15;
#pragma unroll
      for (int rr = 0; rr < 4; ++rr) {
        const int sr = qrow0 + 4 * g + rr;
        o_ws[((size_t)b * SLEN + sr) * DMODEL + d] = f2bf(of[qi][n][rr] * inv[rr]);
      }
    }
  }
}

// ---------------------------------------------------------------------------
// Output projection: out = O @ Wo^T + bo (fp32 out). A (o_ws) already bf16 ->
// direct async gload (64B rows, chunk c^((r>>1)&3)). B reg-staged. One
// barrier per K-step. T1 remap.
// ---------------------------------------------------------------------------
__global__ __launch_bounds__(256)
void gemm_out(const unsigned short* __restrict__ ow,
              const float* __restrict__ Wo, const float* __restrict__ bo,
              float* __restrict__ out)
{
  const int bid = blockIdx.x;                      // 512 = 8 * 64
  const int wg = (bid & 7) * 64 + (bid >> 3);
  const int m0 = (wg >> 3) * 128;
  const int n0 = (wg & 7) * 128;

  const int tid = threadIdx.x;
  const int lane = tid & 63, wid = tid >> 6;
  const int l15 = lane & 15, g = lane >> 4;
  const int wr = wid >> 1, wc = wid & 1;

  // LDS: A bf16 2x8KB @0, B bf16 2x8KB @16384 (32 KB)
  __shared__ __align__(16) char LDS[32768];

  // A async staging: 2 rounds/tile, row = rho*64 + (tid>>2), chunk tid&3
  const int arow = tid >> 2;                // 0..63
  const int ac = tid & 3;
  const unsigned short* Abase = ow + (size_t)(m0 + arow) * DMODEL
                                 + (ac ^ ((arow >> 1) & 3)) * 8;

  const int srow = tid >> 1, sh = tid & 1;
  const float* __restrict__ Bg = Wo + (size_t)(n0 + srow) * DMODEL + sh * 16;
  const unsigned bw0 = (unsigned)(srow * 64) + (((unsigned)(sh * 2))     ^ ((unsigned)((srow >> 1) & 3))) * 16;
  const unsigned bw1 = (unsigned)(srow * 64) + (((unsigned)(sh * 2 + 1)) ^ ((unsigned)((srow >> 1) & 3))) * 16;

  auto stageA = [&](int kt2, int bufsel) {
    char* dst = LDS + bufsel * 8192 + wid * 1024;
    const unsigned short* src = Abase + kt2 * 32;
#pragma unroll
    for (int rho = 0; rho < 2; ++rho)
      gload16(src + (size_t)rho * 64 * DMODEL, dst + rho * 4096);
  };

  f32x4 br4[4];
  auto loadB = [&](int kt2) {
    const float* p = Bg + kt2 * 32;
#pragma unroll
    for (int j = 0; j < 4; ++j) br4[j] = *(const f32x4*)(p + j * 4);
  };
  auto packB = [&](int bufsel) {
    char* Bb = LDS + 16384 + bufsel * 8192;
    i32x4 wv0, wv1;
    wv0[0] = (int)pk(br4[0][0], br4[0][1]); wv0[1] = (int)pk(br4[0][2], br4[0][3]);
    wv0[2] = (int)pk(br4[1][0], br4[1][1]); wv0[3] = (int)pk(br4[1][2], br4[1][3]);
    wv1[0] = (int)pk(br4[2][0], br4[2][1]); wv1[1] = (int)pk(br4[2][2], br4[2][3]);
    wv1[2] = (int)pk(br4[3][0], br4[3][1]); wv1[3] = (int)pk(br4[3][2], br4[3][3]);
    *(i32x4*)(Bb + bw0) = wv0;
    *(i32x4*)(Bb + bw1) = wv1;
  };

  f32x4 acc[4][4];
#pragma unroll
  for (int i = 0; i < 4; ++i)
#pragma unroll
    for (int j = 0; j < 4; ++j) acc[i][j] = zero4();

  stageA(0, 0);
  loadB(0);
  packB(0);
  loadB(1);
  __syncthreads();

  for (int kt = 0; kt < 32; ++kt) {
    const int cur = kt & 1;
    if (kt + 1 < 32) {
      stageA(kt + 1, cur ^ 1);
      packB(cur ^ 1);
    }
    if (kt + 2 < 32) loadB(kt + 2);

    const char* Ab = LDS + cur * 8192;
    const char* Bb = LDS + 16384 + cur * 8192;
    bf16x8 afr[4], bfr[4];
#pragma unroll
    for (int i = 0; i < 4; ++i) {
      const int ra = wr * 64 + i * 16 + l15;
      afr[i] = *(const bf16x8*)(Ab + ra * 64 + ((g ^ ((ra >> 1) & 3)) * 16));
      const int rb = wc * 64 + i * 16 + l15;
      bfr[i] = *(const bf16x8*)(Bb + rb * 64 + ((g ^ ((rb >> 1) & 3)) * 16));
    }
#pragma unroll
    for (int mi = 0; mi < 4; ++mi)
#pragma unroll
      for (int ni = 0; ni < 4; ++ni)
        acc[mi][ni] = __builtin_amdgcn_mfma_f32_16x16x32_bf16(
            afr[mi], bfr[ni], acc[mi][ni], 0, 0, 0);

    if (kt + 1 < 32) __syncthreads();
  }

  float bv4[4];
#pragma unroll
  for (int ni = 0; ni < 4; ++ni) bv4[ni] = bo[n0 + wc * 64 + ni * 16 + l15];
#pragma unroll
  for (int mi = 0; mi < 4; ++mi) {
#pragma unroll
    for (int ni = 0; ni < 4; ++ni) {
      const int n = n0 + wc * 64 + ni * 16 + l15;
#pragma unroll
      for (int rr = 0; rr < 4; ++rr) {
        const int m = m0 + wr * 64 + mi * 16 + 4 * g + rr;
        out[(size_t)m * DMODEL + n] = acc[mi][ni][rr] + bv4[ni];
      }
    }
  }
}

// ---------------------------------------------------------------------------
extern "C" void kernel_launch(void* const* d_in, const int* in_sizes, int n_in,
                              void* d_out, int out_size, void* d_ws, size_t ws_size,
                              hipStream_t stream) {
  const float* query = (const float*)d_in[0];
  const float* key_  = (const float*)d_in[1];
  const float* value = (const float*)d_in[2];
  const int*   mask  = (const int*)d_in[3];
  const float* Wq = (const float*)d_in[4];
  const float* bq = (const float*)d_in[5];
  const float* Wk = (const float*)d_in[6];
  const float* bk = (const float*)d_in[7];
  const float* Wv = (const float*)d_in[8];
  const float* bv = (const float*)d_in[9];
  const float* Wo = (const float*)d_in[10];
  const float* bo = (const float*)d_in[11];
  float* out = (float*)d_out;

  char* ws = (char*)d_ws;
  unsigned short* q_ws = (unsigned short*)(ws);
  unsigned short* k_ws = (unsigned short*)(ws + (size_t)16777216);
  unsigned short* vT   = (unsigned short*)(ws + (size_t)2 * 16777216);
  unsigned short* o_ws = (unsigned short*)(ws + (size_t)3 * 16777216);

  gemm_qkv<<<dim3(1536), 256, 0, stream>>>(query, key_, value,
                                           Wq, bq, Wk, bk, Wv, bv,
                                           q_ws, k_ws, vT);
  attn<<<dim3(64, 16), 256, 0, stream>>>(q_ws, k_ws, vT, mask, o_ws);
  gemm_out<<<dim3(512), 256, 0, stream>>>(o_ws, Wo, bo, out);
}

// Round 6
// 266.583 us; speedup vs baseline: 1.4604x; 1.0325x over previous
//
#include <hip/hip_runtime.h>

// MultiHeadedAttention: B=4, S=2048, H=16, D_K=64, D_MODEL=1024
// Pipeline: [gemm_qkv] -> [flash attn] -> [gemm_out]
// ws layout (64 MiB):
//   q_ws [64][2048][64] bf16 @ 0      (16 MiB)  (pre-scaled by 0.125*log2e)
//   k_ws [64][2048][64] bf16 @ 16MiB  (16 MiB)
//   vT   [64][64][2048] bf16 @ 32MiB  (16 MiB)  (V^T per head: [bh][d][s])
//   o_ws [4][2048][1024] bf16 @ 48MiB (16 MiB)

#define DMODEL 1024
#define SLEN 2048
#define NHEAD 16
#define LOG2E 1.44269504088896340736f

typedef __attribute__((ext_vector_type(4))) float f32x4;
typedef __attribute__((ext_vector_type(8))) short bf16x8;
typedef __attribute__((ext_vector_type(4))) int i32x4;
typedef __attribute__((ext_vector_type(2))) int i32x2;

__device__ __forceinline__ unsigned short f2bf(float f) {
  __bf16 h = (__bf16)f;
  union { __bf16 h; unsigned short u; } cv; cv.h = h; return cv.u;
}
__device__ __forceinline__ unsigned pk(float a, float b) {
  return (unsigned)f2bf(a) | ((unsigned)f2bf(b) << 16);
}
// single-instruction hardware exp2 (TRANS pipe). Plain exp2f() without
// fast-math lowers to the OCML denormal-correct sequence (~10 VALU ops)
// and cost attn 2x in R4.
__device__ __forceinline__ float fexp2(float x) {
  float r;
  asm("v_exp_f32 %0, %1" : "=v"(r) : "v"(x));
  return r;
}
__device__ __forceinline__ f32x4 zero4() {
  f32x4 z; z[0] = 0.f; z[1] = 0.f; z[2] = 0.f; z[3] = 0.f; return z;
}
// async global->LDS, 16B per lane; lds dest wave-uniform base + lane*16
__device__ __forceinline__ void gload16(const void* g, void* l) {
  __builtin_amdgcn_global_load_lds(
      (const __attribute__((address_space(1))) unsigned int*)(uintptr_t)g,
      (__attribute__((address_space(3))) unsigned int*)(uintptr_t)l, 16, 0, 0);
}

// ---------------------------------------------------------------------------
// QKV projection: Y = X @ W^T + b ; M=8192,N=1024,K=1024 per z; out bf16
// per-head layout. BK=32. BOTH A and B are reg-staged fp32 -> packed bf16 ->
// XOR-swizzled LDS (64B rows, chunk c^((r>>1)&3)) -- conversion happens ONCE
// per element at staging, not per consuming wave at read (R5: read-side cvt
// held MfmaUtil at 13%). Global loads issued 2 K-steps ahead (T14). ONE
// __syncthreads per K-step. T1 XCD-chunked grid. z==2: V^T epilogue.
// ---------------------------------------------------------------------------
__global__ __launch_bounds__(256)
void gemm_qkv(const float* __restrict__ xq, const float* __restrict__ xk,
              const float* __restrict__ xv,
              const float* __restrict__ Wq, const float* __restrict__ bq,
              const float* __restrict__ Wk, const float* __restrict__ bk,
              const float* __restrict__ Wv, const float* __restrict__ bv,
              unsigned short* __restrict__ qw, unsigned short* __restrict__ kw,
              unsigned short* __restrict__ vw)
{
  // T1: XCD-chunked bijective remap (1536 = 8 * 192), n fastest within chunk
  const int bid = blockIdx.x;
  const int wg = (bid & 7) * 192 + (bid >> 3);
  const int z = wg >> 9;
  const int r = wg & 511;
  const int m0 = (r >> 3) * 128;
  const int n0 = (r & 7) * 128;

  const float* __restrict__ X    = (z == 0) ? xq : (z == 1) ? xk : xv;
  const float* __restrict__ W    = (z == 0) ? Wq : (z == 1) ? Wk : Wv;
  const float* __restrict__ bias = (z == 0) ? bq : (z == 1) ? bk : bv;
  const float scale = (z == 0) ? 0.125f * LOG2E : 1.0f;

  const int tid = threadIdx.x;
  const int lane = tid & 63, wid = tid >> 6;
  const int l15 = lane & 15, g = lane >> 4;
  const int wr = wid >> 1, wc = wid & 1;

  // LDS: A bf16 2x8KB @0, B bf16 2x8KB @16384 (32 KB total)
  __shared__ __align__(16) char LDS[32768];
  unsigned short* TT = (unsigned short*)LDS;   // epilogue overlay [64][136]

  // staging: thread owns row srow (0..127), k-half sh (16 fp32 each)
  const int srow = tid >> 1, sh = tid & 1;
  const float* __restrict__ Ag = X + (size_t)(m0 + srow) * DMODEL + sh * 16;
  const float* __restrict__ Bg = W + (size_t)(n0 + srow) * DMODEL + sh * 16;
  const unsigned sw0 = (unsigned)(srow * 64) + (((unsigned)(sh * 2))     ^ ((unsigned)((srow >> 1) & 3))) * 16;
  const unsigned sw1 = (unsigned)(srow * 64) + (((unsigned)(sh * 2 + 1)) ^ ((unsigned)((srow >> 1) & 3))) * 16;

  f32x4 ar4[4], br4[4];
  auto loadA = [&](int kt2) {
    const float* p = Ag + kt2 * 32;
#pragma unroll
    for (int j = 0; j < 4; ++j) ar4[j] = *(const f32x4*)(p + j * 4);
  };
  auto loadB = [&](int kt2) {
    const float* p = Bg + kt2 * 32;
#pragma unroll
    for (int j = 0; j < 4; ++j) br4[j] = *(const f32x4*)(p + j * 4);
  };
  auto packA = [&](int bufsel) {
    char* Ab = LDS + bufsel * 8192;
    i32x4 wv0, wv1;
    wv0[0] = (int)pk(ar4[0][0], ar4[0][1]); wv0[1] = (int)pk(ar4[0][2], ar4[0][3]);
    wv0[2] = (int)pk(ar4[1][0], ar4[1][1]); wv0[3] = (int)pk(ar4[1][2], ar4[1][3]);
    wv1[0] = (int)pk(ar4[2][0], ar4[2][1]); wv1[1] = (int)pk(ar4[2][2], ar4[2][3]);
    wv1[2] = (int)pk(ar4[3][0], ar4[3][1]); wv1[3] = (int)pk(ar4[3][2], ar4[3][3]);
    *(i32x4*)(Ab + sw0) = wv0;
    *(i32x4*)(Ab + sw1) = wv1;
  };
  auto packB = [&](int bufsel) {
    char* Bb = LDS + 16384 + bufsel * 8192;
    i32x4 wv0, wv1;
    wv0[0] = (int)pk(br4[0][0], br4[0][1]); wv0[1] = (int)pk(br4[0][2], br4[0][3]);
    wv0[2] = (int)pk(br4[1][0], br4[1][1]); wv0[3] = (int)pk(br4[1][2], br4[1][3]);
    wv1[0] = (int)pk(br4[2][0], br4[2][1]); wv1[1] = (int)pk(br4[2][2], br4[2][3]);
    wv1[2] = (int)pk(br4[3][0], br4[3][1]); wv1[3] = (int)pk(br4[3][2], br4[3][3]);
    *(i32x4*)(Bb + sw0) = wv0;
    *(i32x4*)(Bb + sw1) = wv1;
  };

  f32x4 acc[4][4];
#pragma unroll
  for (int i = 0; i < 4; ++i)
#pragma unroll
    for (int j = 0; j < 4; ++j) acc[i][j] = zero4();

  // prologue: pack tile 0, prefetch tile 1 into regs
  loadA(0); loadB(0);
  packA(0); packB(0);
  loadA(1); loadB(1);
  __syncthreads();

  for (int kt = 0; kt < 32; ++kt) {
    const int cur = kt & 1;
    if (kt + 1 < 32) {
      packA(cur ^ 1);              // regs hold tile kt+1
      packB(cur ^ 1);
    }
    if (kt + 2 < 32) {             // issue global loads for kt+2 (T14)
      loadA(kt + 2);
      loadB(kt + 2);
    }

    // ---- fragments from LDS (both bf16, identical swizzle) ----
    const char* Ab = LDS + cur * 8192;
    const char* Bb = LDS + 16384 + cur * 8192;
    bf16x8 afr[4], bfr[4];
#pragma unroll
    for (int i = 0; i < 4; ++i) {
      const int ra = wr * 64 + i * 16 + l15;
      afr[i] = *(const bf16x8*)(Ab + ra * 64 + ((g ^ ((ra >> 1) & 3)) * 16));
      const int rb = wc * 64 + i * 16 + l15;
      bfr[i] = *(const bf16x8*)(Bb + rb * 64 + ((g ^ ((rb >> 1) & 3)) * 16));
    }
#pragma unroll
    for (int mi = 0; mi < 4; ++mi)
#pragma unroll
      for (int ni = 0; ni < 4; ++ni)
        acc[mi][ni] = __builtin_amdgcn_mfma_f32_16x16x32_bf16(
            afr[mi], bfr[ni], acc[mi][ni], 0, 0, 0);

    if (kt + 1 < 32) __syncthreads();
  }

  float bv4[4];
#pragma unroll
  for (int ni = 0; ni < 4; ++ni) bv4[ni] = bias[n0 + wc * 64 + ni * 16 + l15];

  if (z == 2) {
    // ---- transpose epilogue: store V^T [b*1024 + n][s] ----
    const int bb = m0 >> 11, s0 = m0 & 2047;
#pragma unroll
    for (int p = 0; p < 2; ++p) {
      __syncthreads();
      if (wc == p) {
#pragma unroll
        for (int mi = 0; mi < 4; ++mi)
#pragma unroll
          for (int ni = 0; ni < 4; ++ni)
#pragma unroll
            for (int rr2 = 0; rr2 < 4; ++rr2)
              TT[(ni * 16 + l15) * 136 + wr * 64 + mi * 16 + 4 * g + rr2] =
                  f2bf(acc[mi][ni][rr2] + bv4[ni]);
      }
      __syncthreads();
      const int rr = tid >> 2, cc = (tid & 3) * 32;
      unsigned short* dp = vw + ((size_t)(bb * 1024 + n0 + p * 64 + rr)) * 2048 + s0 + cc;
      const unsigned short* sp = &TT[rr * 136 + cc];
#pragma unroll
      for (int j = 0; j < 4; ++j)
        *(i32x4*)(void*)(dp + j * 8) = *(const i32x4*)(const void*)(sp + j * 8);
    }
    return;
  }

  unsigned short* __restrict__ dst = (z == 0) ? qw : kw;
#pragma unroll
  for (int mi = 0; mi < 4; ++mi) {
#pragma unroll
    for (int ni = 0; ni < 4; ++ni) {
      const int n = n0 + wc * 64 + ni * 16 + l15;
      const int h = n >> 6, d = n & 63;
#pragma unroll
      for (int rr2 = 0; rr2 < 4; ++rr2) {
        const int m = m0 + wr * 64 + mi * 16 + 4 * g + rr2;
        const int b = m >> 11, s = m & 2047;
        const float val = (acc[mi][ni][rr2] + bv4[ni]) * scale;
        dst[((size_t)(b * NHEAD + h) * SLEN + s) * 64 + d] = f2bf(val);
      }
    }
  }
}

// ---------------------------------------------------------------------------
// Flash attention. 4 waves x 32 q-rows (QBLK 128). KVBLK 64, double-buffered
// global_load_lds staging with XOR-swizzled source; exp2-domain online softmax
// with defer-max; mask folded into MFMA C-init.  (unchanged)
// ---------------------------------------------------------------------------
__global__ __launch_bounds__(256, 3)
void attn(const unsigned short* __restrict__ q_ws,
          const unsigned short* __restrict__ k_ws,
          const unsigned short* __restrict__ vT,
          const int* __restrict__ mask,
          unsigned short* __restrict__ o_ws)
{
  const int bh = blockIdx.x;            // 0..63
  const int qt = blockIdx.y;            // 0..15
  const int b = bh >> 4, h = bh & 15;
  const int tid = threadIdx.x, w = tid >> 6, lane = tid & 63;
  const int l15 = lane & 15, g = lane >> 4;

  __shared__ __align__(16) unsigned short Kb[2][64 * 64];
  __shared__ __align__(16) unsigned short Vb[2][64 * 64];
  __shared__ __align__(16) unsigned short Pl[4][16 * 64];
  __shared__ __align__(16) float maskf[2048];

  {
    const int4* mp = (const int4*)(mask + b * SLEN);
    const int4 ma = mp[tid * 2], mb = mp[tid * 2 + 1];
    float4 f0, f1;
    f0.x = ma.x ? 0.f : -1e9f; f0.y = ma.y ? 0.f : -1e9f;
    f0.z = ma.z ? 0.f : -1e9f; f0.w = ma.w ? 0.f : -1e9f;
    f1.x = mb.x ? 0.f : -1e9f; f1.y = mb.y ? 0.f : -1e9f;
    f1.z = mb.z ? 0.f : -1e9f; f1.w = mb.w ? 0.f : -1e9f;
    *(float4*)&maskf[tid * 8]     = f0;
    *(float4*)&maskf[tid * 8 + 4] = f1;
  }

  const size_t head = (size_t)bh * SLEN;
  const int r8 = lane >> 3, c8 = lane & 7;
  const int swz = ((c8 ^ r8) * 16);
  const unsigned pswz = (unsigned)((l15 & 7) << 4);

  const int qbase = qt * 128 + w * 32;
  bf16x8 qf[2][2];
  {
    const unsigned short* qp0 = q_ws + (head + qbase + l15) * 64;
    const unsigned short* qp1 = q_ws + (head + qbase + 16 + l15) * 64;
    qf[0][0] = *(const bf16x8*)(qp0 + g * 8);
    qf[0][1] = *(const bf16x8*)(qp0 + 32 + g * 8);
    qf[1][0] = *(const bf16x8*)(qp1 + g * 8);
    qf[1][1] = *(const bf16x8*)(qp1 + 32 + g * 8);
  }

  auto stage = [&](int kt2, int bufi) {
#pragma unroll
    for (int cl = 0; cl < 2; ++cl) {
      const int rr = w * 16 + cl * 8 + r8;
      const char* gk = (const char*)(k_ws + (head + kt2 * 64 + rr) * 64) + swz;
      gload16(gk, &Kb[bufi][(w * 16 + cl * 8) * 64]);
      const char* gv = (const char*)(vT + ((size_t)(bh * 64 + rr)) * SLEN + kt2 * 64) + swz;
      gload16(gv, &Vb[bufi][(w * 16 + cl * 8) * 64]);
    }
  };

  stage(0, 0);
  __syncthreads();

  float m_run[2] = {-1e30f, -1e30f};
  float l_run[2] = {0.f, 0.f};
  f32x4 of[2][4];
#pragma unroll
  for (int qi = 0; qi < 2; ++qi)
#pragma unroll
    for (int n = 0; n < 4; ++n) of[qi][n] = zero4();

  unsigned short* Pw = (unsigned short*)Pl[w];
  int cur = 0;

  for (int kt = 0; kt < 32; ++kt) {
    if (kt + 1 < 32) stage(kt + 1, cur ^ 1);
    const char* Kc = (const char*)Kb[cur];
    const char* Vc = (const char*)Vb[cur];
    const int kv0 = kt * 64;

    f32x4 mv[4];
#pragma unroll
    for (int s = 0; s < 4; ++s) mv[s] = *(const f32x4*)&maskf[kv0 + s * 16 + g * 4];

#pragma unroll
    for (int qi = 0; qi < 2; ++qi) {
      f32x4 sac[4];
#pragma unroll
      for (int s = 0; s < 4; ++s) {
        const char* kr = Kc + (s * 16 + l15) * 128;
        const bf16x8 kf0 = *(const bf16x8*)(kr + ((unsigned)(g * 16) ^ pswz));
        const bf16x8 kf1 = *(const bf16x8*)(kr + ((unsigned)(64 + g * 16) ^ pswz));
        f32x4 zt = mv[s];
        zt = __builtin_amdgcn_mfma_f32_16x16x32_bf16(kf0, qf[qi][0], zt, 0, 0, 0);
        sac[s] = __builtin_amdgcn_mfma_f32_16x16x32_bf16(kf1, qf[qi][1], zt, 0, 0, 0);
      }

      float tmax = -3.0e38f;
#pragma unroll
      for (int s = 0; s < 4; ++s)
#pragma unroll
        for (int rr = 0; rr < 4; ++rr) tmax = fmaxf(tmax, sac[s][rr]);
      tmax = fmaxf(tmax, __shfl_xor(tmax, 16));
      tmax = fmaxf(tmax, __shfl_xor(tmax, 32));
      if (!__all(tmax <= m_run[qi] + 8.f)) {
        const float mnew = fmaxf(m_run[qi], tmax);
        const float alpha = fexp2(m_run[qi] - mnew);
        float af[4];
#pragma unroll
        for (int rr = 0; rr < 4; ++rr) af[rr] = __shfl(alpha, g * 4 + rr);
#pragma unroll
        for (int n = 0; n < 4; ++n)
#pragma unroll
          for (int rr = 0; rr < 4; ++rr) of[qi][n][rr] *= af[rr];
        l_run[qi] *= alpha;
        m_run[qi] = mnew;
      }
      float psum = 0.f;
      unsigned pr[4][2];
#pragma unroll
      for (int s = 0; s < 4; ++s) {
        const float p0 = fexp2(sac[s][0] - m_run[qi]);
        const float p1 = fexp2(sac[s][1] - m_run[qi]);
        const float p2 = fexp2(sac[s][2] - m_run[qi]);
        const float p3 = fexp2(sac[s][3] - m_run[qi]);
        psum += (p0 + p1) + (p2 + p3);
        pr[s][0] = pk(p0, p1); pr[s][1] = pk(p2, p3);
      }
      l_run[qi] += psum;
#pragma unroll
      for (int s = 0; s < 4; ++s) {
        i32x2 wv; wv[0] = (int)pr[s][0]; wv[1] = (int)pr[s][1];
        *(i32x2*)(void*)((char*)Pw + l15 * 128 + ((unsigned)(s * 32 + g * 8) ^ pswz)) = wv;
      }

#pragma unroll
      for (int k2 = 0; k2 < 2; ++k2) {
        const bf16x8 pa = *(const bf16x8*)(const void*)(
            (const char*)Pw + l15 * 128 + ((unsigned)(k2 * 64 + g * 16) ^ pswz));
#pragma unroll
        for (int n = 0; n < 4; ++n) {
          const bf16x8 vf = *(const bf16x8*)(
              Vc + (n * 16 + l15) * 128 + ((unsigned)(k2 * 64 + g * 16) ^ pswz));
          of[qi][n] = __builtin_amdgcn_mfma_f32_16x16x32_bf16(pa, vf, of[qi][n], 0, 0, 0);
        }
      }
    }
    __syncthreads();
    cur ^= 1;
  }

#pragma unroll
  for (int qi = 0; qi < 2; ++qi) {
    float lt = l_run[qi];
    lt += __shfl_xor(lt, 16);
    lt += __shfl_xor(lt, 32);
    float inv[4];
#pragma unroll
    for (int rr = 0; rr < 4; ++rr) inv[rr] = 1.f / __shfl(lt, g * 4 + rr);
    const int qrow0 = qt * 128 + w * 32 + qi * 16;
#pragma unroll
    for (int n = 0; n < 4; ++n) {
      const int d = h * 64 + n * 16 + l15;
#pragma unroll
      for (int rr = 0; rr < 4; ++rr) {
        const int sr = qrow0 + 4 * g + rr;
        o_ws[((size_t)b * SLEN + sr) * DMODEL + d] = f2bf(of[qi][n][rr] * inv[rr]);
      }
    }
  }
}

// ---------------------------------------------------------------------------
// Output projection: out = O @ Wo^T + bo (fp32 out). A (o_ws) already bf16 ->
// direct async gload (64B rows, chunk c^((r>>1)&3)). B reg-staged. One
// barrier per K-step. T1 remap.  (unchanged)
// ---------------------------------------------------------------------------
__global__ __launch_bounds__(256)
void gemm_out(const unsigned short* __restrict__ ow,
              const float* __restrict__ Wo, const float* __restrict__ bo,
              float* __restrict__ out)
{
  const int bid = blockIdx.x;                      // 512 = 8 * 64
  const int wg = (bid & 7) * 64 + (bid >> 3);
  const int m0 = (wg >> 3) * 128;
  const int n0 = (wg & 7) * 128;

  const int tid = threadIdx.x;
  const int lane = tid & 63, wid = tid >> 6;
  const int l15 = lane & 15, g = lane >> 4;
  const int wr = wid >> 1, wc = wid & 1;

  // LDS: A bf16 2x8KB @0, B bf16 2x8KB @16384 (32 KB)
  __shared__ __align__(16) char LDS[32768];

  // A async staging: 2 rounds/tile, row = rho*64 + (tid>>2), chunk tid&3
  const int arow = tid >> 2;                // 0..63
  const int ac = tid & 3;
  const unsigned short* Abase = ow + (size_t)(m0 + arow) * DMODEL
                                 + (ac ^ ((arow >> 1) & 3)) * 8;

  const int srow = tid >> 1, sh = tid & 1;
  const float* __restrict__ Bg = Wo + (size_t)(n0 + srow) * DMODEL + sh * 16;
  const unsigned bw0 = (unsigned)(srow * 64) + (((unsigned)(sh * 2))     ^ ((unsigned)((srow >> 1) & 3))) * 16;
  const unsigned bw1 = (unsigned)(srow * 64) + (((unsigned)(sh * 2 + 1)) ^ ((unsigned)((srow >> 1) & 3))) * 16;

  auto stageA = [&](int kt2, int bufsel) {
    char* dst = LDS + bufsel * 8192 + wid * 1024;
    const unsigned short* src = Abase + kt2 * 32;
#pragma unroll
    for (int rho = 0; rho < 2; ++rho)
      gload16(src + (size_t)rho * 64 * DMODEL, dst + rho * 4096);
  };

  f32x4 br4[4];
  auto loadB = [&](int kt2) {
    const float* p = Bg + kt2 * 32;
#pragma unroll
    for (int j = 0; j < 4; ++j) br4[j] = *(const f32x4*)(p + j * 4);
  };
  auto packB = [&](int bufsel) {
    char* Bb = LDS + 16384 + bufsel * 8192;
    i32x4 wv0, wv1;
    wv0[0] = (int)pk(br4[0][0], br4[0][1]); wv0[1] = (int)pk(br4[0][2], br4[0][3]);
    wv0[2] = (int)pk(br4[1][0], br4[1][1]); wv0[3] = (int)pk(br4[1][2], br4[1][3]);
    wv1[0] = (int)pk(br4[2][0], br4[2][1]); wv1[1] = (int)pk(br4[2][2], br4[2][3]);
    wv1[2] = (int)pk(br4[3][0], br4[3][1]); wv1[3] = (int)pk(br4[3][2], br4[3][3]);
    *(i32x4*)(Bb + bw0) = wv0;
    *(i32x4*)(Bb + bw1) = wv1;
  };

  f32x4 acc[4][4];
#pragma unroll
  for (int i = 0; i < 4; ++i)
#pragma unroll
    for (int j = 0; j < 4; ++j) acc[i][j] = zero4();

  stageA(0, 0);
  loadB(0);
  packB(0);
  loadB(1);
  __syncthreads();

  for (int kt = 0; kt < 32; ++kt) {
    const int cur = kt & 1;
    if (kt + 1 < 32) {
      stageA(kt + 1, cur ^ 1);
      packB(cur ^ 1);
    }
    if (kt + 2 < 32) loadB(kt + 2);

    const char* Ab = LDS + cur * 8192;
    const char* Bb = LDS + 16384 + cur * 8192;
    bf16x8 afr[4], bfr[4];
#pragma unroll
    for (int i = 0; i < 4; ++i) {
      const int ra = wr * 64 + i * 16 + l15;
      afr[i] = *(const bf16x8*)(Ab + ra * 64 + ((g ^ ((ra >> 1) & 3)) * 16));
      const int rb = wc * 64 + i * 16 + l15;
      bfr[i] = *(const bf16x8*)(Bb + rb * 64 + ((g ^ ((rb >> 1) & 3)) * 16));
    }
#pragma unroll
    for (int mi = 0; mi < 4; ++mi)
#pragma unroll
      for (int ni = 0; ni < 4; ++ni)
        acc[mi][ni] = __builtin_amdgcn_mfma_f32_16x16x32_bf16(
            afr[mi], bfr[ni], acc[mi][ni], 0, 0, 0);

    if (kt + 1 < 32) __syncthreads();
  }

  float bv4[4];
#pragma unroll
  for (int ni = 0; ni < 4; ++ni) bv4[ni] = bo[n0 + wc * 64 + ni * 16 + l15];
#pragma unroll
  for (int mi = 0; mi < 4; ++mi) {
#pragma unroll
    for (int ni = 0; ni < 4; ++ni) {
      const int n = n0 + wc * 64 + ni * 16 + l15;
#pragma unroll
      for (int rr = 0; rr < 4; ++rr) {
        const int m = m0 + wr * 64 + mi * 16 + 4 * g + rr;
        out[(size_t)m * DMODEL + n] = acc[mi][ni][rr] + bv4[ni];
      }
    }
  }
}

// ---------------------------------------------------------------------------
extern "C" void kernel_launch(void* const* d_in, const int* in_sizes, int n_in,
                              void* d_out, int out_size, void* d_ws, size_t ws_size,
                              hipStream_t stream) {
  const float* query = (const float*)d_in[0];
  const float* key_  = (const float*)d_in[1];
  const float* value = (const float*)d_in[2];
  const int*   mask  = (const int*)d_in[3];
  const float* Wq = (const float*)d_in[4];
  const float* bq = (const float*)d_in[5];
  const float* Wk = (const float*)d_in[6];
  const float* bk = (const float*)d_in[7];
  const float* Wv = (const float*)d_in[8];
  const float* bv = (const float*)d_in[9];
  const float* Wo = (const float*)d_in[10];
  const float* bo = (const float*)d_in[11];
  float* out = (float*)d_out;

  char* ws = (char*)d_ws;
  unsigned short* q_ws = (unsigned short*)(ws);
  unsigned short* k_ws = (unsigned short*)(ws + (size_t)16777216);
  unsigned short* vT   = (unsigned short*)(ws + (size_t)2 * 16777216);
  unsigned short* o_ws = (unsigned short*)(ws + (size_t)3 * 16777216);

  gemm_qkv<<<dim3(1536), 256, 0, stream>>>(query, key_, value,
                                           Wq, bq, Wk, bk, Wv, bv,
                                           q_ws, k_ws, vT);
  attn<<<dim3(64, 16), 256, 0, stream>>>(q_ws, k_ws, vT, mask, o_ws);
  gemm_out<<<dim3(512), 256, 0, stream>>>(o_ws, Wo, bo, out);
}